// Round 1
// baseline (1201.333 us; speedup 1.0000x reference)
//
#include <hip/hip_runtime.h>

// ---------------- problem constants ----------------
constexpr int NV = 30000, NR = 1000;
constexpr int EVV = 400000, EVI = 120000, EIV = 120000;
constexpr int ESL = EVV + NV;   // v2v edges + self loops

// ---------------- workspace layout (float units) ----------------
constexpr size_t OFF_DEG    = 0;
constexpr size_t OFF_MEAN   = OFF_DEG + NV;                 // NV*2
constexpr size_t OFF_A      = OFF_MEAN + (size_t)NV * 2;
// phase A (layer 1)
constexpr size_t OFF_HL_VV1 = OFF_A;
constexpr size_t OFF_HR_VV1 = OFF_HL_VV1 + (size_t)NV * 128;
constexpr size_t OFF_HR_IV1 = OFF_HR_VV1 + (size_t)NV * 128;
constexpr size_t OFF_HL_VI1 = OFF_HR_IV1 + (size_t)NV * 128;
constexpr size_t OFF_HL_IV1 = OFF_HL_VI1 + (size_t)NV * 128;
constexpr size_t OFF_HR_VI1 = OFF_HL_IV1 + (size_t)NR * 128;
constexpr size_t OFF_EX_VV1 = OFF_HR_VI1 + (size_t)NR * 128;
constexpr size_t OFF_EX_IV1 = OFF_EX_VV1 + (size_t)ESL * 2;
constexpr size_t OFF_EX_VI1 = OFF_EX_IV1 + (size_t)EIV * 2;
constexpr size_t OFF_DEN_VV1= OFF_EX_VI1 + (size_t)EVI * 2;
constexpr size_t OFF_DEN_IV1= OFF_DEN_VV1 + (size_t)NV * 2;
constexpr size_t OFF_DEN_VI1= OFF_DEN_IV1 + (size_t)NV * 2;
constexpr size_t OFF_V1     = OFF_DEN_VI1 + (size_t)NR * 2;
constexpr size_t OFF_R1     = OFF_V1 + (size_t)NV * 128;
constexpr size_t WS_END_A   = OFF_R1 + (size_t)NR * 128;
// phase B (layer 2) overlays phase A's transform region (v1/r1 preserved)
constexpr size_t OFF_HL_VV2 = OFF_A;
constexpr size_t OFF_HR_VV2 = OFF_HL_VV2 + (size_t)NV * 64;
constexpr size_t OFF_HR_IV2 = OFF_HR_VV2 + (size_t)NV * 64;
constexpr size_t OFF_HL_VI2 = OFF_HR_IV2 + (size_t)NV * 64;
constexpr size_t OFF_HL_IV2 = OFF_HL_VI2 + (size_t)NV * 64;
constexpr size_t OFF_HR_VI2 = OFF_HL_IV2 + (size_t)NR * 64;
constexpr size_t OFF_EX_VV2 = OFF_HR_VI2 + (size_t)NR * 64;
constexpr size_t OFF_EX_IV2 = OFF_EX_VV2 + (size_t)ESL;
constexpr size_t OFF_EX_VI2 = OFF_EX_IV2 + (size_t)EIV;
constexpr size_t OFF_DEN_VV2= OFF_EX_VI2 + (size_t)EVI;
constexpr size_t OFF_DEN_IV2= OFF_DEN_VV2 + (size_t)NV;
constexpr size_t OFF_DEN_VI2= OFF_DEN_IV2 + (size_t)NV;
constexpr size_t OFF_V2     = OFF_DEN_VI2 + (size_t)NR;
constexpr size_t OFF_R2     = OFF_V2 + (size_t)NV * 64;
constexpr size_t WS_END_B   = OFF_R2 + (size_t)NR * 64;
static_assert(WS_END_B <= OFF_V1, "phase B overlay must not clobber v1/r1");

// ---------------- kernels ----------------

// per-dst degree + edge-attr sum (for self-loop 'mean' fill)
__global__ __launch_bounds__(256) void k_deg_sum(const int* __restrict__ dst,
    const float* __restrict__ ea, float* __restrict__ deg, float* __restrict__ sum, int E) {
  int e = blockIdx.x * blockDim.x + threadIdx.x;
  if (e >= E) return;
  int d = dst[e];
  atomicAdd(&deg[d], 1.f);
  atomicAdd(&sum[2 * d],     ea[2 * e]);
  atomicAdd(&sum[2 * d + 1], ea[2 * e + 1]);
}

__global__ __launch_bounds__(256) void k_mean(const float* __restrict__ deg,
    float* __restrict__ sum, int n) {
  int i = blockIdx.x * blockDim.x + threadIdx.x;
  if (i >= n) return;
  float dg = fmaxf(deg[i], 1.f);
  sum[2 * i]     /= dg;
  sum[2 * i + 1] /= dg;
}

// Y[n,C] = X[n,K] @ W[K,C]; block = C threads, processes ROWS rows
template<int K, int C, int ROWS>
__global__ __launch_bounds__(C) void k_rowgemm(const float* __restrict__ X,
    const float* __restrict__ W, float* __restrict__ Y, int n) {
  __shared__ float xs[ROWS][K];
  int r0 = blockIdx.x * ROWS;
  int t = threadIdx.x;
  for (int i = t; i < ROWS * K; i += C) {
    int r = i / K, k = i % K;
    xs[r][k] = (r0 + r < n) ? X[(size_t)(r0 + r) * K + k] : 0.f;
  }
  __syncthreads();
  float acc[ROWS];
#pragma unroll
  for (int r = 0; r < ROWS; r++) acc[r] = 0.f;
  for (int k = 0; k < K; k++) {
    float w = W[(size_t)k * C + t];
#pragma unroll
    for (int r = 0; r < ROWS; r++) acc[r] += xs[r][k] * w;
  }
  for (int r = 0; r < ROWS; r++)
    if (r0 + r < n) Y[(size_t)(r0 + r) * C + t] = acc[r];
}

// per-edge attention: ex = exp(att . leaky_relu(hl[s]+hr[d]+he)), den[d] += ex
// one wave per edge; lane = channel (C=64); self-loop edges appended past Eorig
template<int H>
__global__ __launch_bounds__(256) void k_edge_logits(const int* __restrict__ S,
    const int* __restrict__ D, const float* __restrict__ EA, int Eorig, int Etot,
    const float* __restrict__ mean_ea,
    const float* __restrict__ hl, const float* __restrict__ hr,
    const float* __restrict__ We, const float* __restrict__ att,
    float* __restrict__ ex_out, float* __restrict__ den) {
  int w = (blockIdx.x * blockDim.x + threadIdx.x) >> 6;
  int lane = threadIdx.x & 63;
  if (w >= Etot) return;
  int s, d; float e0, e1;
  if (w < Eorig) { s = S[w]; d = D[w]; e0 = EA[2 * w]; e1 = EA[2 * w + 1]; }
  else { s = w - Eorig; d = s; e0 = mean_ea[2 * s]; e1 = mean_ea[2 * s + 1]; }
#pragma unroll
  for (int h = 0; h < H; h++) {
    int c = h * 64 + lane;
    float he = e0 * We[c] + e1 * We[H * 64 + c];
    float g = hl[(size_t)s * (H * 64) + c] + hr[(size_t)d * (H * 64) + c] + he;
    g = g > 0.f ? g : 0.2f * g;
    float l = g * att[c];
#pragma unroll
    for (int off = 32; off; off >>= 1) l += __shfl_xor(l, off);
    if (lane == 0) {
      float exv = expf(l);
      ex_out[(size_t)w * H + h] = exv;
      atomicAdd(&den[(size_t)d * H + h], exv);
    }
  }
}

// out[d] += (ex/den[d]) * hl[s]
template<int H>
__global__ __launch_bounds__(256) void k_edge_scatter(const int* __restrict__ S,
    const int* __restrict__ D, int Eorig, int Etot,
    const float* __restrict__ ex, const float* __restrict__ den,
    const float* __restrict__ hl, float* __restrict__ out) {
  int w = (blockIdx.x * blockDim.x + threadIdx.x) >> 6;
  int lane = threadIdx.x & 63;
  if (w >= Etot) return;
  int s, d;
  if (w < Eorig) { s = S[w]; d = D[w]; }
  else { s = w - Eorig; d = s; }
#pragma unroll
  for (int h = 0; h < H; h++) {
    float coef = ex[(size_t)w * H + h] / (den[(size_t)d * H + h] + 1e-16f);
    atomicAdd(&out[(size_t)d * (H * 64) + h * 64 + lane],
              coef * hl[(size_t)s * (H * 64) + h * 64 + lane]);
  }
}

__global__ __launch_bounds__(256) void k_bias_elu(float* __restrict__ v,
    const float* __restrict__ b1, const float* __restrict__ b2, int n, int Ctot) {
  int i = blockIdx.x * blockDim.x + threadIdx.x;
  if (i >= n * Ctot) return;
  int c = i % Ctot;
  float x = v[i] + b1[c] + (b2 ? b2[c] : 0.f);
  v[i] = x > 0.f ? x : (expf(x) - 1.f);
}

// layernorm over 64 channels; one wave per row; biases folded in
__global__ __launch_bounds__(256) void k_ln(const float* __restrict__ v,
    const float* __restrict__ b1, const float* __restrict__ b2,
    const float* __restrict__ g, const float* __restrict__ beta,
    float* __restrict__ out, int n) {
  int w = (blockIdx.x * blockDim.x + threadIdx.x) >> 6;
  int lane = threadIdx.x & 63;
  if (w >= n) return;
  float x = v[(size_t)w * 64 + lane] + b1[lane] + (b2 ? b2[lane] : 0.f);
  float s = x;
#pragma unroll
  for (int off = 32; off; off >>= 1) s += __shfl_xor(s, off);
  float mu = s * (1.f / 64.f);
  float dx = x - mu;
  float vs = dx * dx;
#pragma unroll
  for (int off = 32; off; off >>= 1) vs += __shfl_xor(vs, off);
  float var = vs * (1.f / 64.f);
  out[(size_t)w * 64 + lane] = dx * rsqrtf(var + 1e-5f) * g[lane] + beta[lane];
}

// ---------------- launch ----------------
extern "C" void kernel_launch(void* const* d_in, const int* in_sizes, int n_in,
                              void* d_out, int out_size, void* d_ws, size_t ws_size,
                              hipStream_t stream) {
  const float* x_veh  = (const float*)d_in[0];
  const float* x_rsu  = (const float*)d_in[1];
  const float* ea_vv  = (const float*)d_in[2];
  const float* ea_vi  = (const float*)d_in[3];
  const float* ea_iv  = (const float*)d_in[4];
  const int*   src_vv = (const int*)d_in[5];
  const int*   dst_vv = (const int*)d_in[6];
  const int*   src_vi = (const int*)d_in[7];
  const int*   dst_vi = (const int*)d_in[8];
  const int*   src_iv = (const int*)d_in[9];
  const int*   dst_iv = (const int*)d_in[10];
  const float* Wl_vv1 = (const float*)d_in[11];
  const float* Wr_vv1 = (const float*)d_in[12];
  const float* We_vv1 = (const float*)d_in[13];
  const float* att_vv1= (const float*)d_in[14];
  const float* b_vv1  = (const float*)d_in[15];
  const float* Wl_vi1 = (const float*)d_in[16];
  const float* Wr_vi1 = (const float*)d_in[17];
  const float* We_vi1 = (const float*)d_in[18];
  const float* att_vi1= (const float*)d_in[19];
  const float* b_vi1  = (const float*)d_in[20];
  const float* Wl_iv1 = (const float*)d_in[21];
  const float* Wr_iv1 = (const float*)d_in[22];
  const float* We_iv1 = (const float*)d_in[23];
  const float* att_iv1= (const float*)d_in[24];
  const float* b_iv1  = (const float*)d_in[25];
  const float* Wl_vv2 = (const float*)d_in[26];
  const float* Wr_vv2 = (const float*)d_in[27];
  const float* We_vv2 = (const float*)d_in[28];
  const float* att_vv2= (const float*)d_in[29];
  const float* b_vv2  = (const float*)d_in[30];
  const float* Wl_vi2 = (const float*)d_in[31];
  const float* Wr_vi2 = (const float*)d_in[32];
  const float* We_vi2 = (const float*)d_in[33];
  const float* att_vi2= (const float*)d_in[34];
  const float* b_vi2  = (const float*)d_in[35];
  const float* Wl_iv2 = (const float*)d_in[36];
  const float* Wr_iv2 = (const float*)d_in[37];
  const float* We_iv2 = (const float*)d_in[38];
  const float* att_iv2= (const float*)d_in[39];
  const float* b_iv2  = (const float*)d_in[40];
  const float* ln_vg  = (const float*)d_in[41];
  const float* ln_vb  = (const float*)d_in[42];
  const float* ln_rg  = (const float*)d_in[43];
  const float* ln_rb  = (const float*)d_in[44];

  float* ws  = (float*)d_ws;
  float* out = (float*)d_out;

  // zero accumulators (deg+mean, layer-1 dens + v1 + r1)
  hipMemsetAsync(ws + OFF_DEG, 0, (OFF_A - OFF_DEG) * sizeof(float), stream);
  hipMemsetAsync(ws + OFF_DEN_VV1, 0, (WS_END_A - OFF_DEN_VV1) * sizeof(float), stream);

  // self-loop mean edge attrs
  k_deg_sum<<<(EVV + 255) / 256, 256, 0, stream>>>(dst_vv, ea_vv, ws + OFF_DEG, ws + OFF_MEAN, EVV);
  k_mean<<<(NV + 255) / 256, 256, 0, stream>>>(ws + OFF_DEG, ws + OFF_MEAN, NV);

  // layer-1 dense transforms
  k_rowgemm<16, 128, 16><<<(NV + 15) / 16, 128, 0, stream>>>(x_veh, Wl_vv1, ws + OFF_HL_VV1, NV);
  k_rowgemm<16, 128, 16><<<(NV + 15) / 16, 128, 0, stream>>>(x_veh, Wr_vv1, ws + OFF_HR_VV1, NV);
  k_rowgemm<16, 128, 16><<<(NV + 15) / 16, 128, 0, stream>>>(x_veh, Wr_iv1, ws + OFF_HR_IV1, NV);
  k_rowgemm<16, 128, 16><<<(NV + 15) / 16, 128, 0, stream>>>(x_veh, Wl_vi1, ws + OFF_HL_VI1, NV);
  k_rowgemm<8, 128, 16><<<(NR + 15) / 16, 128, 0, stream>>>(x_rsu, Wl_iv1, ws + OFF_HL_IV1, NR);
  k_rowgemm<8, 128, 16><<<(NR + 15) / 16, 128, 0, stream>>>(x_rsu, Wr_vi1, ws + OFF_HR_VI1, NR);

  // layer-1 edge attention
  k_edge_logits<2><<<(ESL + 3) / 4, 256, 0, stream>>>(src_vv, dst_vv, ea_vv, EVV, ESL,
      ws + OFF_MEAN, ws + OFF_HL_VV1, ws + OFF_HR_VV1, We_vv1, att_vv1,
      ws + OFF_EX_VV1, ws + OFF_DEN_VV1);
  k_edge_logits<2><<<(EIV + 3) / 4, 256, 0, stream>>>(src_iv, dst_iv, ea_iv, EIV, EIV,
      nullptr, ws + OFF_HL_IV1, ws + OFF_HR_IV1, We_iv1, att_iv1,
      ws + OFF_EX_IV1, ws + OFF_DEN_IV1);
  k_edge_logits<2><<<(EVI + 3) / 4, 256, 0, stream>>>(src_vi, dst_vi, ea_vi, EVI, EVI,
      nullptr, ws + OFF_HL_VI1, ws + OFF_HR_VI1, We_vi1, att_vi1,
      ws + OFF_EX_VI1, ws + OFF_DEN_VI1);

  k_edge_scatter<2><<<(ESL + 3) / 4, 256, 0, stream>>>(src_vv, dst_vv, EVV, ESL,
      ws + OFF_EX_VV1, ws + OFF_DEN_VV1, ws + OFF_HL_VV1, ws + OFF_V1);
  k_edge_scatter<2><<<(EIV + 3) / 4, 256, 0, stream>>>(src_iv, dst_iv, EIV, EIV,
      ws + OFF_EX_IV1, ws + OFF_DEN_IV1, ws + OFF_HL_IV1, ws + OFF_V1);
  k_edge_scatter<2><<<(EVI + 3) / 4, 256, 0, stream>>>(src_vi, dst_vi, EVI, EVI,
      ws + OFF_EX_VI1, ws + OFF_DEN_VI1, ws + OFF_HL_VI1, ws + OFF_R1);

  k_bias_elu<<<(NV * 128 + 255) / 256, 256, 0, stream>>>(ws + OFF_V1, b_vv1, b_iv1, NV, 128);
  k_bias_elu<<<(NR * 128 + 255) / 256, 256, 0, stream>>>(ws + OFF_R1, b_vi1, nullptr, NR, 128);

  // zero layer-2 accumulators (after layer-1 consumers are done; stream-ordered)
  hipMemsetAsync(ws + OFF_DEN_VV2, 0, (WS_END_B - OFF_DEN_VV2) * sizeof(float), stream);

  // layer-2 dense transforms
  k_rowgemm<128, 64, 32><<<(NV + 31) / 32, 64, 0, stream>>>(ws + OFF_V1, Wl_vv2, ws + OFF_HL_VV2, NV);
  k_rowgemm<128, 64, 32><<<(NV + 31) / 32, 64, 0, stream>>>(ws + OFF_V1, Wr_vv2, ws + OFF_HR_VV2, NV);
  k_rowgemm<128, 64, 32><<<(NV + 31) / 32, 64, 0, stream>>>(ws + OFF_V1, Wr_iv2, ws + OFF_HR_IV2, NV);
  k_rowgemm<128, 64, 32><<<(NV + 31) / 32, 64, 0, stream>>>(ws + OFF_V1, Wl_vi2, ws + OFF_HL_VI2, NV);
  k_rowgemm<128, 64, 32><<<(NR + 31) / 32, 64, 0, stream>>>(ws + OFF_R1, Wl_iv2, ws + OFF_HL_IV2, NR);
  k_rowgemm<128, 64, 32><<<(NR + 31) / 32, 64, 0, stream>>>(ws + OFF_R1, Wr_vi2, ws + OFF_HR_VI2, NR);

  // layer-2 edge attention
  k_edge_logits<1><<<(ESL + 3) / 4, 256, 0, stream>>>(src_vv, dst_vv, ea_vv, EVV, ESL,
      ws + OFF_MEAN, ws + OFF_HL_VV2, ws + OFF_HR_VV2, We_vv2, att_vv2,
      ws + OFF_EX_VV2, ws + OFF_DEN_VV2);
  k_edge_logits<1><<<(EIV + 3) / 4, 256, 0, stream>>>(src_iv, dst_iv, ea_iv, EIV, EIV,
      nullptr, ws + OFF_HL_IV2, ws + OFF_HR_IV2, We_iv2, att_iv2,
      ws + OFF_EX_IV2, ws + OFF_DEN_IV2);
  k_edge_logits<1><<<(EVI + 3) / 4, 256, 0, stream>>>(src_vi, dst_vi, ea_vi, EVI, EVI,
      nullptr, ws + OFF_HL_VI2, ws + OFF_HR_VI2, We_vi2, att_vi2,
      ws + OFF_EX_VI2, ws + OFF_DEN_VI2);

  k_edge_scatter<1><<<(ESL + 3) / 4, 256, 0, stream>>>(src_vv, dst_vv, EVV, ESL,
      ws + OFF_EX_VV2, ws + OFF_DEN_VV2, ws + OFF_HL_VV2, ws + OFF_V2);
  k_edge_scatter<1><<<(EIV + 3) / 4, 256, 0, stream>>>(src_iv, dst_iv, EIV, EIV,
      ws + OFF_EX_IV2, ws + OFF_DEN_IV2, ws + OFF_HL_IV2, ws + OFF_V2);
  k_edge_scatter<1><<<(EVI + 3) / 4, 256, 0, stream>>>(src_vi, dst_vi, EVI, EVI,
      ws + OFF_EX_VI2, ws + OFF_DEN_VI2, ws + OFF_HL_VI2, ws + OFF_R2);

  // layernorm + write output (veh rows then rsu rows)
  k_ln<<<(NV + 3) / 4, 256, 0, stream>>>(ws + OFF_V2, b_vv2, b_iv2, ln_vg, ln_vb, out, NV);
  k_ln<<<(NR + 3) / 4, 256, 0, stream>>>(ws + OFF_R2, b_vi2, nullptr, ln_rg, ln_rb,
                                         out + (size_t)NV * 64, NR);
  (void)in_sizes; (void)n_in; (void)out_size; (void)ws_size;
}

// Round 2
// 957.418 us; speedup vs baseline: 1.2548x; 1.2548x over previous
//
#include <hip/hip_runtime.h>

// ---------------- problem constants ----------------
constexpr int NV = 30000, NR = 1000;
constexpr int EVV = 400000, EVI = 120000, EIV = 120000;

// ---------------- workspace layout (float units) ----------------
constexpr size_t OFF_MEAN   = 0;                         // NV*2 (self-loop mean ea)
constexpr size_t OFF_CNT_VV = OFF_MEAN + (size_t)NV * 2; // int
constexpr size_t OFF_PTR_VV = OFF_CNT_VV + NV;           // NV+1
constexpr size_t OFF_CUR_VV = OFF_PTR_VV + NV + 1;
constexpr size_t OFF_EID_VV = OFF_CUR_VV + NV;
constexpr size_t OFF_CNT_IV = OFF_EID_VV + EVV;
constexpr size_t OFF_PTR_IV = OFF_CNT_IV + NV;
constexpr size_t OFF_CUR_IV = OFF_PTR_IV + NV + 1;
constexpr size_t OFF_EID_IV = OFF_CUR_IV + NV;
constexpr size_t OFF_CNT_VI = OFF_EID_IV + EIV;
constexpr size_t OFF_PTR_VI = OFF_CNT_VI + NR;
constexpr size_t OFF_CUR_VI = OFF_PTR_VI + NR + 1;
constexpr size_t OFF_EID_VI = OFF_CUR_VI + NR;
constexpr size_t OFF_CSR_END= OFF_EID_VI + EVI;
// layer-1 transforms
constexpr size_t OFF_H      = OFF_CSR_END;
constexpr size_t OFF_HL_VV1 = OFF_H;
constexpr size_t OFF_HR_VV1 = OFF_HL_VV1 + (size_t)NV * 128;
constexpr size_t OFF_HR_IV1 = OFF_HR_VV1 + (size_t)NV * 128;
constexpr size_t OFF_HL_VI1 = OFF_HR_IV1 + (size_t)NV * 128;
constexpr size_t OFF_HL_IV1 = OFF_HL_VI1 + (size_t)NV * 128;
constexpr size_t OFF_HR_VI1 = OFF_HL_IV1 + (size_t)NR * 128;
constexpr size_t OFF_V1     = OFF_HR_VI1 + (size_t)NR * 128;
constexpr size_t OFF_R1     = OFF_V1 + (size_t)NV * 128;
constexpr size_t WS_END     = OFF_R1 + (size_t)NR * 128;
// layer-2 transforms overlay layer-1 region (v1/r1 preserved)
constexpr size_t OFF_HL_VV2 = OFF_H;
constexpr size_t OFF_HR_VV2 = OFF_HL_VV2 + (size_t)NV * 64;
constexpr size_t OFF_HR_IV2 = OFF_HR_VV2 + (size_t)NV * 64;
constexpr size_t OFF_HL_VI2 = OFF_HR_IV2 + (size_t)NV * 64;
constexpr size_t OFF_HL_IV2 = OFF_HL_VI2 + (size_t)NV * 64;
constexpr size_t OFF_HR_VI2 = OFF_HL_IV2 + (size_t)NR * 64;
constexpr size_t OFF_H2_END = OFF_HR_VI2 + (size_t)NR * 64;
static_assert(OFF_H2_END <= OFF_V1, "layer-2 overlay must not clobber v1/r1");

// ---------------- CSR build ----------------
__global__ __launch_bounds__(256) void k_count(const int* __restrict__ dst,
    int* __restrict__ cnt, int E) {
  int e = blockIdx.x * blockDim.x + threadIdx.x;
  if (e < E) atomicAdd(&cnt[dst[e]], 1);
}

__global__ __launch_bounds__(256) void k_sum_ea(const int* __restrict__ dst,
    const float* __restrict__ ea, float* __restrict__ sum, int E) {
  int e = blockIdx.x * blockDim.x + threadIdx.x;
  if (e >= E) return;
  int d = dst[e];
  atomicAdd(&sum[2 * d],     ea[2 * e]);
  atomicAdd(&sum[2 * d + 1], ea[2 * e + 1]);
}

__global__ __launch_bounds__(256) void k_mean(const int* __restrict__ cnt,
    float* __restrict__ mean, int n) {
  int i = blockIdx.x * blockDim.x + threadIdx.x;
  if (i >= n) return;
  float dg = fmaxf((float)cnt[i], 1.f);
  mean[2 * i]     /= dg;
  mean[2 * i + 1] /= dg;
}

// exclusive scan of cnt[0..n) into ptr[0..n], single block of 1024
__global__ __launch_bounds__(1024) void k_scan(const int* __restrict__ cnt,
    int* __restrict__ ptr, int n) {
  __shared__ int tsum[1024];
  int t = threadIdx.x;
  int per = (n + 1023) >> 10;
  int base = t * per;
  int s = 0;
  for (int i = 0; i < per; i++) { int idx = base + i; if (idx < n) s += cnt[idx]; }
  tsum[t] = s;
  for (int off = 1; off < 1024; off <<= 1) {
    __syncthreads();
    int v = (t >= off) ? tsum[t - off] : 0;
    __syncthreads();
    tsum[t] += v;
  }
  __syncthreads();
  int run = tsum[t] - s;
  for (int i = 0; i < per; i++) {
    int idx = base + i;
    if (idx < n) { ptr[idx] = run; run += cnt[idx]; }
  }
  if (t == 1023) ptr[n] = tsum[1023];
}

__global__ __launch_bounds__(256) void k_fill(const int* __restrict__ dst,
    const int* __restrict__ ptr, int* __restrict__ cur, int* __restrict__ eid, int E) {
  int e = blockIdx.x * blockDim.x + threadIdx.x;
  if (e >= E) return;
  int d = dst[e];
  int p = atomicAdd(&cur[d], 1);
  eid[ptr[d] + p] = e;
}

// ---------------- dense transforms: Y_i = X @ W_i (shared X staging) ----------------
template<int K, int C, int ROWS, int NW>
__global__ __launch_bounds__(C) void k_rowgemmN(const float* __restrict__ X,
    const float* __restrict__ W0, const float* __restrict__ W1,
    const float* __restrict__ W2, const float* __restrict__ W3,
    float* __restrict__ Y0, float* __restrict__ Y1,
    float* __restrict__ Y2, float* __restrict__ Y3, int n) {
  __shared__ float xs[ROWS][K];
  int r0 = blockIdx.x * ROWS;
  int t = threadIdx.x;
  for (int i = t; i < ROWS * K; i += C) {
    int r = i / K, k = i % K;
    xs[r][k] = (r0 + r < n) ? X[(size_t)(r0 + r) * K + k] : 0.f;
  }
  __syncthreads();
  const float* Ws[4] = {W0, W1, W2, W3};
  float* Ys[4] = {Y0, Y1, Y2, Y3};
#pragma unroll
  for (int wi = 0; wi < NW; wi++) {
    const float* __restrict__ W = Ws[wi];
    float* __restrict__ Y = Ys[wi];
    float acc[ROWS];
#pragma unroll
    for (int r = 0; r < ROWS; r++) acc[r] = 0.f;
    for (int k = 0; k < K; k++) {
      float w = W[(size_t)k * C + t];
#pragma unroll
      for (int r = 0; r < ROWS; r++) acc[r] += xs[r][k] * w;
    }
    for (int r = 0; r < ROWS; r++)
      if (r0 + r < n) Y[(size_t)(r0 + r) * C + t] = acc[r];
  }
}

// ---------------- fused per-dst GATv2 aggregation (CSR gather) ----------------
// one wave per dst node; lane = channel within head; single-pass softmax
template<int H>
__device__ __forceinline__ void gat_rel(int d, int lane,
    const int* __restrict__ ptr, const int* __restrict__ eid,
    const int* __restrict__ src, const float* __restrict__ ea,
    const float* __restrict__ mean_ea,   // non-null => add self-loop (s=d, ea=mean)
    const float* __restrict__ hl, const float* __restrict__ hr,
    const float* __restrict__ We, const float* __restrict__ att,
    float* out_c) {
  float hrc[H], attc[H], we0[H], we1[H], acc[H], den[H];
#pragma unroll
  for (int h = 0; h < H; h++) {
    int c = h * 64 + lane;
    hrc[h] = hr[(size_t)d * (H * 64) + c];
    attc[h] = att[c];
    we0[h] = We[c];
    we1[h] = We[H * 64 + c];
    acc[h] = 0.f; den[h] = 0.f;
  }
  auto body = [&](int s, float e0, float e1) {
#pragma unroll
    for (int h = 0; h < H; h++) {
      float hlv = hl[(size_t)s * (H * 64) + h * 64 + lane];
      float g = hlv + hrc[h] + e0 * we0[h] + e1 * we1[h];
      g = g > 0.f ? g : 0.2f * g;
      float l = g * attc[h];
#pragma unroll
      for (int o = 32; o; o >>= 1) l += __shfl_xor(l, o);
      float ex = __expf(l);
      acc[h] += ex * hlv;
      den[h] += ex;
    }
  };
  int b = ptr[d], en = ptr[d + 1];
  for (int i = b; i < en; i++) {
    int e = eid[i];
    body(src[e], ea[2 * e], ea[2 * e + 1]);
  }
  if (mean_ea) body(d, mean_ea[2 * d], mean_ea[2 * d + 1]);
#pragma unroll
  for (int h = 0; h < H; h++) out_c[h] += acc[h] / (den[h] + 1e-16f);
}

// layer-1 vehicle rows: vv(+self-loop) + iv, bias, ELU
__global__ __launch_bounds__(256) void k_gat_v1(
    const int* ptr_vv, const int* eid_vv, const int* src_vv, const float* ea_vv,
    const float* mean_ea, const float* hl_vv, const float* hr_vv,
    const float* We_vv, const float* att_vv,
    const int* ptr_iv, const int* eid_iv, const int* src_iv, const float* ea_iv,
    const float* hl_iv, const float* hr_iv, const float* We_iv, const float* att_iv,
    const float* b1, const float* b2, float* __restrict__ out) {
  int w = (blockIdx.x * blockDim.x + threadIdx.x) >> 6;
  int lane = threadIdx.x & 63;
  if (w >= NV) return;
  float oc[2] = {0.f, 0.f};
  gat_rel<2>(w, lane, ptr_vv, eid_vv, src_vv, ea_vv, mean_ea, hl_vv, hr_vv, We_vv, att_vv, oc);
  gat_rel<2>(w, lane, ptr_iv, eid_iv, src_iv, ea_iv, nullptr, hl_iv, hr_iv, We_iv, att_iv, oc);
#pragma unroll
  for (int h = 0; h < 2; h++) {
    int c = h * 64 + lane;
    float x = oc[h] + b1[c] + b2[c];
    out[(size_t)w * 128 + c] = x > 0.f ? x : __expf(x) - 1.f;
  }
}

// layer-1 rsu rows: vi only, bias, ELU
__global__ __launch_bounds__(256) void k_gat_r1(
    const int* ptr_vi, const int* eid_vi, const int* src_vi, const float* ea_vi,
    const float* hl_vi, const float* hr_vi, const float* We_vi, const float* att_vi,
    const float* b1, float* __restrict__ out) {
  int w = (blockIdx.x * blockDim.x + threadIdx.x) >> 6;
  int lane = threadIdx.x & 63;
  if (w >= NR) return;
  float oc[2] = {0.f, 0.f};
  gat_rel<2>(w, lane, ptr_vi, eid_vi, src_vi, ea_vi, nullptr, hl_vi, hr_vi, We_vi, att_vi, oc);
#pragma unroll
  for (int h = 0; h < 2; h++) {
    int c = h * 64 + lane;
    float x = oc[h] + b1[c];
    out[(size_t)w * 128 + c] = x > 0.f ? x : __expf(x) - 1.f;
  }
}

__device__ __forceinline__ void ln_write(int lane, float x,
    const float* __restrict__ g, const float* __restrict__ beta,
    float* __restrict__ out) {
  float s = x;
#pragma unroll
  for (int o = 32; o; o >>= 1) s += __shfl_xor(s, o);
  float mu = s * (1.f / 64.f);
  float dx = x - mu;
  float vs = dx * dx;
#pragma unroll
  for (int o = 32; o; o >>= 1) vs += __shfl_xor(vs, o);
  out[lane] = dx * rsqrtf(vs * (1.f / 64.f) + 1e-5f) * g[lane] + beta[lane];
}

// layer-2 vehicle rows: vv(+self) + iv, bias, LayerNorm -> final out
__global__ __launch_bounds__(256) void k_gat_v2(
    const int* ptr_vv, const int* eid_vv, const int* src_vv, const float* ea_vv,
    const float* mean_ea, const float* hl_vv, const float* hr_vv,
    const float* We_vv, const float* att_vv,
    const int* ptr_iv, const int* eid_iv, const int* src_iv, const float* ea_iv,
    const float* hl_iv, const float* hr_iv, const float* We_iv, const float* att_iv,
    const float* b1, const float* b2, const float* g, const float* beta,
    float* __restrict__ out) {
  int w = (blockIdx.x * blockDim.x + threadIdx.x) >> 6;
  int lane = threadIdx.x & 63;
  if (w >= NV) return;
  float oc[1] = {0.f};
  gat_rel<1>(w, lane, ptr_vv, eid_vv, src_vv, ea_vv, mean_ea, hl_vv, hr_vv, We_vv, att_vv, oc);
  gat_rel<1>(w, lane, ptr_iv, eid_iv, src_iv, ea_iv, nullptr, hl_iv, hr_iv, We_iv, att_iv, oc);
  float x = oc[0] + b1[lane] + b2[lane];
  ln_write(lane, x, g, beta, out + (size_t)w * 64);
}

// layer-2 rsu rows: vi, bias, LayerNorm -> final out (offset NV rows)
__global__ __launch_bounds__(256) void k_gat_r2(
    const int* ptr_vi, const int* eid_vi, const int* src_vi, const float* ea_vi,
    const float* hl_vi, const float* hr_vi, const float* We_vi, const float* att_vi,
    const float* b1, const float* g, const float* beta, float* __restrict__ out) {
  int w = (blockIdx.x * blockDim.x + threadIdx.x) >> 6;
  int lane = threadIdx.x & 63;
  if (w >= NR) return;
  float oc[1] = {0.f};
  gat_rel<1>(w, lane, ptr_vi, eid_vi, src_vi, ea_vi, nullptr, hl_vi, hr_vi, We_vi, att_vi, oc);
  float x = oc[0] + b1[lane];
  ln_write(lane, x, g, beta, out + (size_t)(NV + w) * 64);
}

// ---------------- launch ----------------
extern "C" void kernel_launch(void* const* d_in, const int* in_sizes, int n_in,
                              void* d_out, int out_size, void* d_ws, size_t ws_size,
                              hipStream_t stream) {
  const float* x_veh  = (const float*)d_in[0];
  const float* x_rsu  = (const float*)d_in[1];
  const float* ea_vv  = (const float*)d_in[2];
  const float* ea_vi  = (const float*)d_in[3];
  const float* ea_iv  = (const float*)d_in[4];
  const int*   src_vv = (const int*)d_in[5];
  const int*   dst_vv = (const int*)d_in[6];
  const int*   src_vi = (const int*)d_in[7];
  const int*   dst_vi = (const int*)d_in[8];
  const int*   src_iv = (const int*)d_in[9];
  const int*   dst_iv = (const int*)d_in[10];
  const float* Wl_vv1 = (const float*)d_in[11];
  const float* Wr_vv1 = (const float*)d_in[12];
  const float* We_vv1 = (const float*)d_in[13];
  const float* att_vv1= (const float*)d_in[14];
  const float* b_vv1  = (const float*)d_in[15];
  const float* Wl_vi1 = (const float*)d_in[16];
  const float* Wr_vi1 = (const float*)d_in[17];
  const float* We_vi1 = (const float*)d_in[18];
  const float* att_vi1= (const float*)d_in[19];
  const float* b_vi1  = (const float*)d_in[20];
  const float* Wl_iv1 = (const float*)d_in[21];
  const float* Wr_iv1 = (const float*)d_in[22];
  const float* We_iv1 = (const float*)d_in[23];
  const float* att_iv1= (const float*)d_in[24];
  const float* b_iv1  = (const float*)d_in[25];
  const float* Wl_vv2 = (const float*)d_in[26];
  const float* Wr_vv2 = (const float*)d_in[27];
  const float* We_vv2 = (const float*)d_in[28];
  const float* att_vv2= (const float*)d_in[29];
  const float* b_vv2  = (const float*)d_in[30];
  const float* Wl_vi2 = (const float*)d_in[31];
  const float* Wr_vi2 = (const float*)d_in[32];
  const float* We_vi2 = (const float*)d_in[33];
  const float* att_vi2= (const float*)d_in[34];
  const float* b_vi2  = (const float*)d_in[35];
  const float* Wl_iv2 = (const float*)d_in[36];
  const float* Wr_iv2 = (const float*)d_in[37];
  const float* We_iv2 = (const float*)d_in[38];
  const float* att_iv2= (const float*)d_in[39];
  const float* b_iv2  = (const float*)d_in[40];
  const float* ln_vg  = (const float*)d_in[41];
  const float* ln_vb  = (const float*)d_in[42];
  const float* ln_rg  = (const float*)d_in[43];
  const float* ln_rb  = (const float*)d_in[44];

  float* ws  = (float*)d_ws;
  float* out = (float*)d_out;

  int* cnt_vv = (int*)(ws + OFF_CNT_VV); int* ptr_vv = (int*)(ws + OFF_PTR_VV);
  int* cur_vv = (int*)(ws + OFF_CUR_VV); int* eid_vv = (int*)(ws + OFF_EID_VV);
  int* cnt_iv = (int*)(ws + OFF_CNT_IV); int* ptr_iv = (int*)(ws + OFF_PTR_IV);
  int* cur_iv = (int*)(ws + OFF_CUR_IV); int* eid_iv = (int*)(ws + OFF_EID_IV);
  int* cnt_vi = (int*)(ws + OFF_CNT_VI); int* ptr_vi = (int*)(ws + OFF_PTR_VI);
  int* cur_vi = (int*)(ws + OFF_CUR_VI); int* eid_vi = (int*)(ws + OFF_EID_VI);

  // zero mean + all CSR state (cnt/cur must be 0 every call)
  hipMemsetAsync(ws, 0, OFF_CSR_END * sizeof(float), stream);

  // CSR build + self-loop mean edge attrs
  k_count<<<(EVV + 255) / 256, 256, 0, stream>>>(dst_vv, cnt_vv, EVV);
  k_count<<<(EIV + 255) / 256, 256, 0, stream>>>(dst_iv, cnt_iv, EIV);
  k_count<<<(EVI + 255) / 256, 256, 0, stream>>>(dst_vi, cnt_vi, EVI);
  k_sum_ea<<<(EVV + 255) / 256, 256, 0, stream>>>(dst_vv, ea_vv, ws + OFF_MEAN, EVV);
  k_scan<<<1, 1024, 0, stream>>>(cnt_vv, ptr_vv, NV);
  k_scan<<<1, 1024, 0, stream>>>(cnt_iv, ptr_iv, NV);
  k_scan<<<1, 1024, 0, stream>>>(cnt_vi, ptr_vi, NR);
  k_mean<<<(NV + 255) / 256, 256, 0, stream>>>(cnt_vv, ws + OFF_MEAN, NV);
  k_fill<<<(EVV + 255) / 256, 256, 0, stream>>>(dst_vv, ptr_vv, cur_vv, eid_vv, EVV);
  k_fill<<<(EIV + 255) / 256, 256, 0, stream>>>(dst_iv, ptr_iv, cur_iv, eid_iv, EIV);
  k_fill<<<(EVI + 255) / 256, 256, 0, stream>>>(dst_vi, ptr_vi, cur_vi, eid_vi, EVI);

  // layer-1 dense transforms (shared-X batched)
  k_rowgemmN<16, 128, 16, 4><<<(NV + 15) / 16, 128, 0, stream>>>(x_veh,
      Wl_vv1, Wr_vv1, Wr_iv1, Wl_vi1,
      ws + OFF_HL_VV1, ws + OFF_HR_VV1, ws + OFF_HR_IV1, ws + OFF_HL_VI1, NV);
  k_rowgemmN<8, 128, 16, 2><<<(NR + 15) / 16, 128, 0, stream>>>(x_rsu,
      Wl_iv1, Wr_vi1, nullptr, nullptr,
      ws + OFF_HL_IV1, ws + OFF_HR_VI1, nullptr, nullptr, NR);

  // layer-1 fused aggregation
  k_gat_v1<<<(NV + 3) / 4, 256, 0, stream>>>(
      ptr_vv, eid_vv, src_vv, ea_vv, ws + OFF_MEAN,
      ws + OFF_HL_VV1, ws + OFF_HR_VV1, We_vv1, att_vv1,
      ptr_iv, eid_iv, src_iv, ea_iv,
      ws + OFF_HL_IV1, ws + OFF_HR_IV1, We_iv1, att_iv1,
      b_vv1, b_iv1, ws + OFF_V1);
  k_gat_r1<<<(NR + 3) / 4, 256, 0, stream>>>(
      ptr_vi, eid_vi, src_vi, ea_vi,
      ws + OFF_HL_VI1, ws + OFF_HR_VI1, We_vi1, att_vi1,
      b_vi1, ws + OFF_R1);

  // layer-2 dense transforms
  k_rowgemmN<128, 64, 32, 4><<<(NV + 31) / 32, 64, 0, stream>>>(ws + OFF_V1,
      Wl_vv2, Wr_vv2, Wr_iv2, Wl_vi2,
      ws + OFF_HL_VV2, ws + OFF_HR_VV2, ws + OFF_HR_IV2, ws + OFF_HL_VI2, NV);
  k_rowgemmN<128, 64, 32, 2><<<(NR + 31) / 32, 64, 0, stream>>>(ws + OFF_R1,
      Wl_iv2, Wr_vi2, nullptr, nullptr,
      ws + OFF_HL_IV2, ws + OFF_HR_VI2, nullptr, nullptr, NR);

  // layer-2 fused aggregation + LayerNorm -> out
  k_gat_v2<<<(NV + 3) / 4, 256, 0, stream>>>(
      ptr_vv, eid_vv, src_vv, ea_vv, ws + OFF_MEAN,
      ws + OFF_HL_VV2, ws + OFF_HR_VV2, We_vv2, att_vv2,
      ptr_iv, eid_iv, src_iv, ea_iv,
      ws + OFF_HL_IV2, ws + OFF_HR_IV2, We_iv2, att_iv2,
      b_vv2, b_iv2, ln_vg, ln_vb, out);
  k_gat_r2<<<(NR + 3) / 4, 256, 0, stream>>>(
      ptr_vi, eid_vi, src_vi, ea_vi,
      ws + OFF_HL_VI2, ws + OFF_HR_VI2, We_vi2, att_vi2,
      b_vi2, ln_rg, ln_rb, out);
  (void)in_sizes; (void)n_in; (void)out_size; (void)ws_size;
}

// Round 3
// 587.409 us; speedup vs baseline: 2.0451x; 1.6299x over previous
//
#include <hip/hip_runtime.h>

// ---------------- problem constants ----------------
constexpr int NV = 30000, NR = 1000;
constexpr int EVV = 400000, EVI = 120000, EIV = 120000;

// ---------------- workspace layout (float units) ----------------
// zero-region (memset each call): mean + cnt/cur for all rels
constexpr size_t OFF_MEAN   = 0;                          // 2*NV
constexpr size_t OFF_CNT_VV = OFF_MEAN + (size_t)NV * 2;  // NV
constexpr size_t OFF_CUR_VV = OFF_CNT_VV + NV;
constexpr size_t OFF_CNT_IV = OFF_CUR_VV + NV;
constexpr size_t OFF_CUR_IV = OFF_CNT_IV + NV;
constexpr size_t OFF_CNT_VI = OFF_CUR_IV + NV;
constexpr size_t OFF_CUR_VI = OFF_CNT_VI + NR;
constexpr size_t ZERO_END   = OFF_CUR_VI + NR;
// written-every-call region
constexpr size_t OFF_PTR_VV = ZERO_END;                   // NV+1
constexpr size_t OFF_PTR_IV = OFF_PTR_VV + NV + 1;        // NV+1
constexpr size_t OFF_PTR_VI = OFF_PTR_IV + NV + 1;        // NR+1
constexpr size_t OFF_SRC_VV = OFF_PTR_VI + NR + 1;        // EVV (int)
constexpr size_t OFF_EA_VV  = OFF_SRC_VV + EVV;           // 2*EVV
constexpr size_t OFF_SRC_IV = OFF_EA_VV + (size_t)EVV*2;
constexpr size_t OFF_EA_IV  = OFF_SRC_IV + EIV;
constexpr size_t OFF_SRC_VI = OFF_EA_IV + (size_t)EIV*2;
constexpr size_t OFF_EA_VI  = OFF_SRC_VI + EVI;
constexpr size_t OFF_H      = OFF_EA_VI + (size_t)EVI*2;
// layer-1 transforms (head-interleaved storage: chan c -> (c&63)*2+(c>>6))
constexpr size_t OFF_HL_VV1 = OFF_H;
constexpr size_t OFF_HR_VV1 = OFF_HL_VV1 + (size_t)NV * 128;
constexpr size_t OFF_HR_IV1 = OFF_HR_VV1 + (size_t)NV * 128;
constexpr size_t OFF_HL_VI1 = OFF_HR_IV1 + (size_t)NV * 128;
constexpr size_t OFF_HL_IV1 = OFF_HL_VI1 + (size_t)NV * 128;
constexpr size_t OFF_HR_VI1 = OFF_HL_IV1 + (size_t)NR * 128;
constexpr size_t OFF_V1     = OFF_HR_VI1 + (size_t)NR * 128;   // standard layout
constexpr size_t OFF_R1     = OFF_V1 + (size_t)NV * 128;       // standard layout
constexpr size_t WS_END     = OFF_R1 + (size_t)NR * 128;
// layer-2 transforms overlay layer-1 region (v1/r1 preserved); standard layout
constexpr size_t OFF_HL_VV2 = OFF_H;
constexpr size_t OFF_HR_VV2 = OFF_HL_VV2 + (size_t)NV * 64;
constexpr size_t OFF_HR_IV2 = OFF_HR_VV2 + (size_t)NV * 64;
constexpr size_t OFF_HL_VI2 = OFF_HR_IV2 + (size_t)NV * 64;
constexpr size_t OFF_HL_IV2 = OFF_HL_VI2 + (size_t)NV * 64;
constexpr size_t OFF_HR_VI2 = OFF_HL_IV2 + (size_t)NR * 64;
constexpr size_t OFF_H2_END = OFF_HR_VI2 + (size_t)NR * 64;
static_assert(OFF_H2_END <= OFF_V1, "layer-2 overlay must not clobber v1/r1");

// ---------------- CSR build ----------------
__global__ __launch_bounds__(256) void k_prep(
    const int* __restrict__ dvv, const int* __restrict__ div_, const int* __restrict__ dvi,
    const float* __restrict__ ea_vv,
    int* __restrict__ cvv, int* __restrict__ civ, int* __restrict__ cvi,
    float* __restrict__ mean) {
  int t = blockIdx.x * blockDim.x + threadIdx.x;
  if (t < EVV) {
    int d = dvv[t];
    atomicAdd(&cvv[d], 1);
    atomicAdd(&mean[2 * d],     ea_vv[2 * t]);
    atomicAdd(&mean[2 * d + 1], ea_vv[2 * t + 1]);
  } else if (t < EVV + EIV) {
    atomicAdd(&civ[div_[t - EVV]], 1);
  } else if (t < EVV + EIV + EVI) {
    atomicAdd(&cvi[dvi[t - EVV - EIV]], 1);
  }
}

__global__ __launch_bounds__(1024) void k_scan3(
    const int* c0, int* p0, int n0,
    const int* c1, int* p1, int n1,
    const int* c2, int* p2, int n2) {
  const int* cnt = blockIdx.x == 0 ? c0 : blockIdx.x == 1 ? c1 : c2;
  int* ptr = blockIdx.x == 0 ? p0 : blockIdx.x == 1 ? p1 : p2;
  int n = blockIdx.x == 0 ? n0 : blockIdx.x == 1 ? n1 : n2;
  __shared__ int tsum[1024];
  int t = threadIdx.x;
  int per = (n + 1023) >> 10;
  int base = t * per;
  int s = 0;
  for (int i = 0; i < per; i++) { int idx = base + i; if (idx < n) s += cnt[idx]; }
  tsum[t] = s;
  for (int off = 1; off < 1024; off <<= 1) {
    __syncthreads();
    int v = (t >= off) ? tsum[t - off] : 0;
    __syncthreads();
    tsum[t] += v;
  }
  __syncthreads();
  int run = tsum[t] - s;
  for (int i = 0; i < per; i++) {
    int idx = base + i;
    if (idx < n) { ptr[idx] = run; run += cnt[idx]; }
  }
  if (t == 1023) ptr[n] = tsum[1023];
}

__global__ __launch_bounds__(256) void k_mean(const int* __restrict__ cnt,
    float* __restrict__ mean, int n) {
  int i = blockIdx.x * blockDim.x + threadIdx.x;
  if (i >= n) return;
  float dg = fmaxf((float)cnt[i], 1.f);
  mean[2 * i]     /= dg;
  mean[2 * i + 1] /= dg;
}

// fill CSR slots with materialized src + edge-attr (coalesced consumption later)
__global__ __launch_bounds__(256) void k_fill3(
    const int* __restrict__ svv, const int* __restrict__ dvv, const float* __restrict__ eavv,
    const int* __restrict__ siv, const int* __restrict__ div_, const float* __restrict__ eaiv,
    const int* __restrict__ svi, const int* __restrict__ dvi, const float* __restrict__ eavi,
    const int* __restrict__ pvv, int* __restrict__ uvv, int* __restrict__ csvv, float* __restrict__ cevv,
    const int* __restrict__ piv, int* __restrict__ uiv, int* __restrict__ csiv, float* __restrict__ ceiv,
    const int* __restrict__ pvi, int* __restrict__ uvi, int* __restrict__ csvi, float* __restrict__ cevi) {
  int t = blockIdx.x * blockDim.x + threadIdx.x;
  if (t < EVV) {
    int e = t, d = dvv[e];
    int idx = pvv[d] + atomicAdd(&uvv[d], 1);
    csvv[idx] = svv[e];
    cevv[2 * idx] = eavv[2 * e]; cevv[2 * idx + 1] = eavv[2 * e + 1];
  } else if (t < EVV + EIV) {
    int e = t - EVV, d = div_[e];
    int idx = piv[d] + atomicAdd(&uiv[d], 1);
    csiv[idx] = siv[e];
    ceiv[2 * idx] = eaiv[2 * e]; ceiv[2 * idx + 1] = eaiv[2 * e + 1];
  } else if (t < EVV + EIV + EVI) {
    int e = t - EVV - EIV, d = dvi[e];
    int idx = pvi[d] + atomicAdd(&uvi[d], 1);
    csvi[idx] = svi[e];
    cevi[2 * idx] = eavi[2 * e]; cevi[2 * idx + 1] = eavi[2 * e + 1];
  }
}

// ---------------- layer-1 GEMM: K in {16,8}, C=128, interleaved output ----------------
// block 256 = 2 col-groups of 128; group g computes weights {g, g+2} (or just g if NW==2)
template<int K, int NW>
__global__ __launch_bounds__(256) void k_gemm1(const float* __restrict__ X,
    const float* __restrict__ W0, const float* __restrict__ W1,
    const float* __restrict__ W2, const float* __restrict__ W3,
    float* __restrict__ Y0, float* __restrict__ Y1,
    float* __restrict__ Y2, float* __restrict__ Y3, int n) {
  constexpr int ROWS = 32;
  __shared__ float xs[ROWS][K];
  int r0 = blockIdx.x * ROWS;
  int tid = threadIdx.x;
  int col = tid & 127, grp = tid >> 7;
  for (int i = tid; i < ROWS * K; i += 256) {
    int gi = r0 * K + i;
    ((float*)xs)[i] = (gi < n * K) ? X[gi] : 0.f;
  }
  __syncthreads();
  const float* Ws[4] = {W0, W1, W2, W3};
  float* Ys[4] = {Y0, Y1, Y2, Y3};
  int oidx = ((col & 63) << 1) + (col >> 6);   // head-interleaved storage index
  for (int rep = 0; rep < NW / 2; rep++) {
    int wi = grp + rep * 2;
    const float* __restrict__ W = Ws[wi];
    float* __restrict__ Y = Ys[wi];
    float acc[ROWS];
#pragma unroll
    for (int r = 0; r < ROWS; r++) acc[r] = 0.f;
    for (int k4 = 0; k4 < K / 4; k4++) {
      float w0 = W[(4 * k4 + 0) * 128 + col];
      float w1 = W[(4 * k4 + 1) * 128 + col];
      float w2 = W[(4 * k4 + 2) * 128 + col];
      float w3 = W[(4 * k4 + 3) * 128 + col];
#pragma unroll
      for (int r = 0; r < ROWS; r++) {
        float4 x4 = *(const float4*)&xs[r][4 * k4];
        acc[r] = fmaf(x4.x, w0, acc[r]);
        acc[r] = fmaf(x4.y, w1, acc[r]);
        acc[r] = fmaf(x4.z, w2, acc[r]);
        acc[r] = fmaf(x4.w, w3, acc[r]);
      }
    }
    for (int r = 0; r < ROWS; r++)
      if (r0 + r < n) Y[(size_t)(r0 + r) * 128 + oidx] = acc[r];
  }
}

// ---------------- layer-2 GEMM: K=128, C=64, standard output ----------------
// block = 64*NW threads; wave wi computes weight wi over the shared X tile
template<int NW>
__global__ __launch_bounds__(64 * NW) void k_gemm2(const float* __restrict__ X,
    const float* __restrict__ W0, const float* __restrict__ W1,
    const float* __restrict__ W2, const float* __restrict__ W3,
    float* __restrict__ Y0, float* __restrict__ Y1,
    float* __restrict__ Y2, float* __restrict__ Y3, int n) {
  constexpr int ROWS = 32, K = 128;
  __shared__ float xs[ROWS][K];
  int r0 = blockIdx.x * ROWS;
  int tid = threadIdx.x;
  int lane = tid & 63, wv = tid >> 6;
  for (int i = tid; i < ROWS * K; i += 64 * NW) {
    int gi = r0 * K + i;
    ((float*)xs)[i] = (gi < n * K) ? X[gi] : 0.f;
  }
  __syncthreads();
  const float* Ws[4] = {W0, W1, W2, W3};
  float* Ys[4] = {Y0, Y1, Y2, Y3};
  const float* __restrict__ W = Ws[wv];
  float* __restrict__ Y = Ys[wv];
  float acc[ROWS];
#pragma unroll
  for (int r = 0; r < ROWS; r++) acc[r] = 0.f;
  for (int k4 = 0; k4 < K / 4; k4++) {
    float w0 = W[(4 * k4 + 0) * 64 + lane];
    float w1 = W[(4 * k4 + 1) * 64 + lane];
    float w2 = W[(4 * k4 + 2) * 64 + lane];
    float w3 = W[(4 * k4 + 3) * 64 + lane];
#pragma unroll
    for (int r = 0; r < ROWS; r++) {
      float4 x4 = *(const float4*)&xs[r][4 * k4];
      acc[r] = fmaf(x4.x, w0, acc[r]);
      acc[r] = fmaf(x4.y, w1, acc[r]);
      acc[r] = fmaf(x4.z, w2, acc[r]);
      acc[r] = fmaf(x4.w, w3, acc[r]);
    }
  }
  for (int r = 0; r < ROWS; r++)
    if (r0 + r < n) Y[(size_t)(r0 + r) * 64 + lane] = acc[r];
}

// ---------------- fused GATv2 aggregation ----------------
// accumulates raw (acc, den) for one relation; edges strided across nw waves
template<int H, bool ILV>
__device__ __forceinline__ void gat_rel_acc(int d, int lane, int wv, int nw,
    bool self_loop, const float* __restrict__ mean_ea,
    const int* __restrict__ ptr, const int* __restrict__ srcc,
    const float* __restrict__ eac,
    const float* __restrict__ hl, const float* __restrict__ hr,
    const float* __restrict__ We, const float* __restrict__ att,
    float* acc, float* den) {
  float hrc[H], attc[H], we0[H], we1[H];
  if (ILV) {
    const float2 h2 = *(const float2*)&hr[(size_t)d * 128 + lane * 2];
    hrc[0] = h2.x; if (H > 1) hrc[1] = h2.y;
  } else {
#pragma unroll
    for (int h = 0; h < H; h++) hrc[h] = hr[(size_t)d * (H * 64) + h * 64 + lane];
  }
#pragma unroll
  for (int h = 0; h < H; h++) {
    attc[h] = att[h * 64 + lane];
    we0[h] = We[h * 64 + lane];
    we1[h] = We[H * 64 + h * 64 + lane];
  }
  auto body = [&](int s, float e0, float e1) {
    float hlv[H];
    if (ILV) {
      const float2 t = *(const float2*)&hl[(size_t)s * 128 + lane * 2];
      hlv[0] = t.x; if (H > 1) hlv[1] = t.y;
    } else {
#pragma unroll
      for (int h = 0; h < H; h++) hlv[h] = hl[(size_t)s * (H * 64) + h * 64 + lane];
    }
    float l[H];
#pragma unroll
    for (int h = 0; h < H; h++) {
      float g = hlv[h] + hrc[h] + e0 * we0[h] + e1 * we1[h];
      g = g > 0.f ? g : 0.2f * g;
      l[h] = g * attc[h];
    }
#pragma unroll
    for (int o = 32; o; o >>= 1)
#pragma unroll
      for (int h = 0; h < H; h++) l[h] += __shfl_xor(l[h], o);
#pragma unroll
    for (int h = 0; h < H; h++) {
      float ex = __expf(l[h]);
      acc[h] += ex * hlv[h];
      den[h] += ex;
    }
  };
  int b = ptr[d], en = ptr[d + 1];
  for (int i = b + wv; i < en; i += nw)
    body(srcc[i], eac[2 * i], eac[2 * i + 1]);
  if (self_loop && wv == 0)
    body(d, mean_ea[2 * d], mean_ea[2 * d + 1]);
}

// layer-1 vehicle rows: vv(+self) + iv, bias, ELU -> v1 (standard layout)
__global__ __launch_bounds__(256) void k_gat_v1(
    const int* ptr_vv, const int* src_vv, const float* ea_vv, const float* mean_ea,
    const float* hl_vv, const float* hr_vv, const float* We_vv, const float* att_vv,
    const int* ptr_iv, const int* src_iv, const float* ea_iv,
    const float* hl_iv, const float* hr_iv, const float* We_iv, const float* att_iv,
    const float* b1, const float* b2, float* __restrict__ out) {
  int w = (blockIdx.x * blockDim.x + threadIdx.x) >> 6;
  int lane = threadIdx.x & 63;
  if (w >= NV) return;
  float oc[2] = {0.f, 0.f};
  {
    float acc[2] = {0.f, 0.f}, den[2] = {0.f, 0.f};
    gat_rel_acc<2, true>(w, lane, 0, 1, true, mean_ea, ptr_vv, src_vv, ea_vv,
                         hl_vv, hr_vv, We_vv, att_vv, acc, den);
    oc[0] += acc[0] / (den[0] + 1e-16f); oc[1] += acc[1] / (den[1] + 1e-16f);
  }
  {
    float acc[2] = {0.f, 0.f}, den[2] = {0.f, 0.f};
    gat_rel_acc<2, true>(w, lane, 0, 1, false, nullptr, ptr_iv, src_iv, ea_iv,
                         hl_iv, hr_iv, We_iv, att_iv, acc, den);
    oc[0] += acc[0] / (den[0] + 1e-16f); oc[1] += acc[1] / (den[1] + 1e-16f);
  }
#pragma unroll
  for (int h = 0; h < 2; h++) {
    int c = h * 64 + lane;
    float x = oc[h] + b1[c] + b2[c];
    out[(size_t)w * 128 + c] = x > 0.f ? x : __expf(x) - 1.f;
  }
}

// layer-1 rsu rows: vi only; one block (4 waves) per dst; bias, ELU -> r1
__global__ __launch_bounds__(256) void k_gat_r1(
    const int* ptr_vi, const int* src_vi, const float* ea_vi,
    const float* hl_vi, const float* hr_vi, const float* We_vi, const float* att_vi,
    const float* b1, float* __restrict__ out) {
  int d = blockIdx.x;
  int lane = threadIdx.x & 63, wv = threadIdx.x >> 6;
  float acc[2] = {0.f, 0.f}, den[2] = {0.f, 0.f};
  gat_rel_acc<2, true>(d, lane, wv, 4, false, nullptr, ptr_vi, src_vi, ea_vi,
                       hl_vi, hr_vi, We_vi, att_vi, acc, den);
  __shared__ float pa[4][2][64], pd[4][2][64];
  pa[wv][0][lane] = acc[0]; pa[wv][1][lane] = acc[1];
  pd[wv][0][lane] = den[0]; pd[wv][1][lane] = den[1];
  __syncthreads();
  if (wv == 0) {
#pragma unroll
    for (int j = 1; j < 4; j++) {
      acc[0] += pa[j][0][lane]; acc[1] += pa[j][1][lane];
      den[0] += pd[j][0][lane]; den[1] += pd[j][1][lane];
    }
#pragma unroll
    for (int h = 0; h < 2; h++) {
      int c = h * 64 + lane;
      float x = acc[h] / (den[h] + 1e-16f) + b1[c];
      out[(size_t)d * 128 + c] = x > 0.f ? x : __expf(x) - 1.f;
    }
  }
}

__device__ __forceinline__ void ln_write(int lane, float x,
    const float* __restrict__ g, const float* __restrict__ beta,
    float* __restrict__ out) {
  float s = x;
#pragma unroll
  for (int o = 32; o; o >>= 1) s += __shfl_xor(s, o);
  float mu = s * (1.f / 64.f);
  float dx = x - mu;
  float vs = dx * dx;
#pragma unroll
  for (int o = 32; o; o >>= 1) vs += __shfl_xor(vs, o);
  out[lane] = dx * rsqrtf(vs * (1.f / 64.f) + 1e-5f) * g[lane] + beta[lane];
}

// layer-2 vehicle rows: vv(+self) + iv, bias, LayerNorm -> final out
__global__ __launch_bounds__(256) void k_gat_v2(
    const int* ptr_vv, const int* src_vv, const float* ea_vv, const float* mean_ea,
    const float* hl_vv, const float* hr_vv, const float* We_vv, const float* att_vv,
    const int* ptr_iv, const int* src_iv, const float* ea_iv,
    const float* hl_iv, const float* hr_iv, const float* We_iv, const float* att_iv,
    const float* b1, const float* b2, const float* g, const float* beta,
    float* __restrict__ out) {
  int w = (blockIdx.x * blockDim.x + threadIdx.x) >> 6;
  int lane = threadIdx.x & 63;
  if (w >= NV) return;
  float oc = 0.f;
  {
    float acc[1] = {0.f}, den[1] = {0.f};
    gat_rel_acc<1, false>(w, lane, 0, 1, true, mean_ea, ptr_vv, src_vv, ea_vv,
                          hl_vv, hr_vv, We_vv, att_vv, acc, den);
    oc += acc[0] / (den[0] + 1e-16f);
  }
  {
    float acc[1] = {0.f}, den[1] = {0.f};
    gat_rel_acc<1, false>(w, lane, 0, 1, false, nullptr, ptr_iv, src_iv, ea_iv,
                          hl_iv, hr_iv, We_iv, att_iv, acc, den);
    oc += acc[0] / (den[0] + 1e-16f);
  }
  float x = oc + b1[lane] + b2[lane];
  ln_write(lane, x, g, beta, out + (size_t)w * 64);
}

// layer-2 rsu rows: vi; one block per dst; bias, LayerNorm -> final out (+NV rows)
__global__ __launch_bounds__(256) void k_gat_r2(
    const int* ptr_vi, const int* src_vi, const float* ea_vi,
    const float* hl_vi, const float* hr_vi, const float* We_vi, const float* att_vi,
    const float* b1, const float* g, const float* beta, float* __restrict__ out) {
  int d = blockIdx.x;
  int lane = threadIdx.x & 63, wv = threadIdx.x >> 6;
  float acc[1] = {0.f}, den[1] = {0.f};
  gat_rel_acc<1, false>(d, lane, wv, 4, false, nullptr, ptr_vi, src_vi, ea_vi,
                        hl_vi, hr_vi, We_vi, att_vi, acc, den);
  __shared__ float pa[4][64], pd[4][64];
  pa[wv][lane] = acc[0]; pd[wv][lane] = den[0];
  __syncthreads();
  if (wv == 0) {
#pragma unroll
    for (int j = 1; j < 4; j++) { acc[0] += pa[j][lane]; den[0] += pd[j][lane]; }
    float x = acc[0] / (den[0] + 1e-16f) + b1[lane];
    ln_write(lane, x, g, beta, out + (size_t)(NV + d) * 64);
  }
}

// ---------------- launch ----------------
extern "C" void kernel_launch(void* const* d_in, const int* in_sizes, int n_in,
                              void* d_out, int out_size, void* d_ws, size_t ws_size,
                              hipStream_t stream) {
  const float* x_veh  = (const float*)d_in[0];
  const float* x_rsu  = (const float*)d_in[1];
  const float* ea_vv  = (const float*)d_in[2];
  const float* ea_vi  = (const float*)d_in[3];
  const float* ea_iv  = (const float*)d_in[4];
  const int*   src_vv = (const int*)d_in[5];
  const int*   dst_vv = (const int*)d_in[6];
  const int*   src_vi = (const int*)d_in[7];
  const int*   dst_vi = (const int*)d_in[8];
  const int*   src_iv = (const int*)d_in[9];
  const int*   dst_iv = (const int*)d_in[10];
  const float* Wl_vv1 = (const float*)d_in[11];
  const float* Wr_vv1 = (const float*)d_in[12];
  const float* We_vv1 = (const float*)d_in[13];
  const float* att_vv1= (const float*)d_in[14];
  const float* b_vv1  = (const float*)d_in[15];
  const float* Wl_vi1 = (const float*)d_in[16];
  const float* Wr_vi1 = (const float*)d_in[17];
  const float* We_vi1 = (const float*)d_in[18];
  const float* att_vi1= (const float*)d_in[19];
  const float* b_vi1  = (const float*)d_in[20];
  const float* Wl_iv1 = (const float*)d_in[21];
  const float* Wr_iv1 = (const float*)d_in[22];
  const float* We_iv1 = (const float*)d_in[23];
  const float* att_iv1= (const float*)d_in[24];
  const float* b_iv1  = (const float*)d_in[25];
  const float* Wl_vv2 = (const float*)d_in[26];
  const float* Wr_vv2 = (const float*)d_in[27];
  const float* We_vv2 = (const float*)d_in[28];
  const float* att_vv2= (const float*)d_in[29];
  const float* b_vv2  = (const float*)d_in[30];
  const float* Wl_vi2 = (const float*)d_in[31];
  const float* Wr_vi2 = (const float*)d_in[32];
  const float* We_vi2 = (const float*)d_in[33];
  const float* att_vi2= (const float*)d_in[34];
  const float* b_vi2  = (const float*)d_in[35];
  const float* Wl_iv2 = (const float*)d_in[36];
  const float* Wr_iv2 = (const float*)d_in[37];
  const float* We_iv2 = (const float*)d_in[38];
  const float* att_iv2= (const float*)d_in[39];
  const float* b_iv2  = (const float*)d_in[40];
  const float* ln_vg  = (const float*)d_in[41];
  const float* ln_vb  = (const float*)d_in[42];
  const float* ln_rg  = (const float*)d_in[43];
  const float* ln_rb  = (const float*)d_in[44];

  float* ws  = (float*)d_ws;
  float* out = (float*)d_out;

  int* cnt_vv = (int*)(ws + OFF_CNT_VV); int* cur_vv = (int*)(ws + OFF_CUR_VV);
  int* cnt_iv = (int*)(ws + OFF_CNT_IV); int* cur_iv = (int*)(ws + OFF_CUR_IV);
  int* cnt_vi = (int*)(ws + OFF_CNT_VI); int* cur_vi = (int*)(ws + OFF_CUR_VI);
  int* ptr_vv = (int*)(ws + OFF_PTR_VV);
  int* ptr_iv = (int*)(ws + OFF_PTR_IV);
  int* ptr_vi = (int*)(ws + OFF_PTR_VI);
  int* csrc_vv = (int*)(ws + OFF_SRC_VV); float* cea_vv = ws + OFF_EA_VV;
  int* csrc_iv = (int*)(ws + OFF_SRC_IV); float* cea_iv = ws + OFF_EA_IV;
  int* csrc_vi = (int*)(ws + OFF_SRC_VI); float* cea_vi = ws + OFF_EA_VI;

  constexpr int ETOT = EVV + EIV + EVI;

  hipMemsetAsync(ws, 0, ZERO_END * sizeof(float), stream);

  k_prep<<<(ETOT + 255) / 256, 256, 0, stream>>>(dst_vv, dst_iv, dst_vi, ea_vv,
      cnt_vv, cnt_iv, cnt_vi, ws + OFF_MEAN);
  k_scan3<<<3, 1024, 0, stream>>>(cnt_vv, ptr_vv, NV, cnt_iv, ptr_iv, NV, cnt_vi, ptr_vi, NR);
  k_mean<<<(NV + 255) / 256, 256, 0, stream>>>(cnt_vv, ws + OFF_MEAN, NV);
  k_fill3<<<(ETOT + 255) / 256, 256, 0, stream>>>(
      src_vv, dst_vv, ea_vv, src_iv, dst_iv, ea_iv, src_vi, dst_vi, ea_vi,
      ptr_vv, cur_vv, csrc_vv, cea_vv,
      ptr_iv, cur_iv, csrc_iv, cea_iv,
      ptr_vi, cur_vi, csrc_vi, cea_vi);

  // layer-1 dense transforms (head-interleaved outputs)
  k_gemm1<16, 4><<<(NV + 31) / 32, 256, 0, stream>>>(x_veh,
      Wl_vv1, Wr_vv1, Wr_iv1, Wl_vi1,
      ws + OFF_HL_VV1, ws + OFF_HR_VV1, ws + OFF_HR_IV1, ws + OFF_HL_VI1, NV);
  k_gemm1<8, 2><<<(NR + 31) / 32, 256, 0, stream>>>(x_rsu,
      Wl_iv1, Wr_vi1, nullptr, nullptr,
      ws + OFF_HL_IV1, ws + OFF_HR_VI1, nullptr, nullptr, NR);

  // layer-1 fused aggregation
  k_gat_v1<<<(NV + 3) / 4, 256, 0, stream>>>(
      ptr_vv, csrc_vv, cea_vv, ws + OFF_MEAN,
      ws + OFF_HL_VV1, ws + OFF_HR_VV1, We_vv1, att_vv1,
      ptr_iv, csrc_iv, cea_iv,
      ws + OFF_HL_IV1, ws + OFF_HR_IV1, We_iv1, att_iv1,
      b_vv1, b_iv1, ws + OFF_V1);
  k_gat_r1<<<NR, 256, 0, stream>>>(
      ptr_vi, csrc_vi, cea_vi,
      ws + OFF_HL_VI1, ws + OFF_HR_VI1, We_vi1, att_vi1,
      b_vi1, ws + OFF_R1);

  // layer-2 dense transforms (standard outputs)
  k_gemm2<4><<<(NV + 31) / 32, 256, 0, stream>>>(ws + OFF_V1,
      Wl_vv2, Wr_vv2, Wr_iv2, Wl_vi2,
      ws + OFF_HL_VV2, ws + OFF_HR_VV2, ws + OFF_HR_IV2, ws + OFF_HL_VI2, NV);
  k_gemm2<2><<<(NR + 31) / 32, 128, 0, stream>>>(ws + OFF_R1,
      Wl_iv2, Wr_vi2, nullptr, nullptr,
      ws + OFF_HL_IV2, ws + OFF_HR_VI2, nullptr, nullptr, NR);

  // layer-2 fused aggregation + LayerNorm -> out
  k_gat_v2<<<(NV + 3) / 4, 256, 0, stream>>>(
      ptr_vv, csrc_vv, cea_vv, ws + OFF_MEAN,
      ws + OFF_HL_VV2, ws + OFF_HR_VV2, We_vv2, att_vv2,
      ptr_iv, csrc_iv, cea_iv,
      ws + OFF_HL_IV2, ws + OFF_HR_IV2, We_iv2, att_iv2,
      b_vv2, b_iv2, ln_vg, ln_vb, out);
  k_gat_r2<<<NR, 256, 0, stream>>>(
      ptr_vi, csrc_vi, cea_vi,
      ws + OFF_HL_VI2, ws + OFF_HR_VI2, We_vi2, att_vi2,
      b_vi2, ln_rg, ln_rb, out);
  (void)in_sizes; (void)n_in; (void)out_size; (void)ws_size;
}

// Round 4
// 513.848 us; speedup vs baseline: 2.3379x; 1.1432x over previous
//
#include <hip/hip_runtime.h>
#include <hip/hip_fp16.h>

// ---------------- problem constants ----------------
constexpr int NV = 30000, NR = 1000;
constexpr int EVV = 400000, EVI = 120000, EIV = 120000;
constexpr int ETOT = EVV + EIV + EVI;
constexpr int VB = (NV + 3) / 4;   // veh blocks in merged gat kernels

struct __align__(8) Edge { int s; __half2 ea; };

// ---------------- workspace layout (float units) ----------------
constexpr size_t OFF_CNT_VV = 0;                       // NV
constexpr size_t OFF_CUR_VV = OFF_CNT_VV + NV;
constexpr size_t OFF_CNT_IV = OFF_CUR_VV + NV;
constexpr size_t OFF_CUR_IV = OFF_CNT_IV + NV;
constexpr size_t OFF_CNT_VI = OFF_CUR_IV + NV;
constexpr size_t OFF_CUR_VI = OFF_CNT_VI + NR;
constexpr size_t ZERO_END   = OFF_CUR_VI + NR;         // 122000 (even)
constexpr size_t OFF_PTR_VV = ZERO_END;                // NV+2 (pad for 8B align)
constexpr size_t OFF_PTR_IV = OFF_PTR_VV + NV + 2;
constexpr size_t OFF_PTR_VI = OFF_PTR_IV + NV + 2;
constexpr size_t OFF_MEAN   = OFF_PTR_VI + NR + 2;     // 2*NV
constexpr size_t OFF_E_VV   = OFF_MEAN + (size_t)NV * 2;   // Edge = 2 floats
constexpr size_t OFF_E_IV   = OFF_E_VV + (size_t)EVV * 2;
constexpr size_t OFF_E_VI   = OFF_E_IV + (size_t)EIV * 2;
constexpr size_t OFF_H      = OFF_E_VI + (size_t)EVI * 2;
// layer-1 tables: 128 halves/row = 64 float-units/row (head-interleaved)
constexpr size_t OFF_HL_VV1 = OFF_H;
constexpr size_t OFF_HR_VV1 = OFF_HL_VV1 + (size_t)NV * 64;
constexpr size_t OFF_HR_IV1 = OFF_HR_VV1 + (size_t)NV * 64;
constexpr size_t OFF_HL_VI1 = OFF_HR_IV1 + (size_t)NV * 64;
constexpr size_t OFF_HL_IV1 = OFF_HL_VI1 + (size_t)NV * 64;
constexpr size_t OFF_HR_VI1 = OFF_HL_IV1 + (size_t)NR * 64;
constexpr size_t L1_END     = OFF_HR_VI1 + (size_t)NR * 64;
// v1/r1: fp16 standard channel order (128 halves/row)
constexpr size_t OFF_V1     = L1_END;
constexpr size_t OFF_R1     = OFF_V1 + (size_t)NV * 64;
constexpr size_t WS_END     = OFF_R1 + (size_t)NR * 64;
// layer-2 tables overlay layer-1 region: 64 halves/row = 32 float-units
constexpr size_t OFF_HL_VV2 = OFF_H;
constexpr size_t OFF_HR_VV2 = OFF_HL_VV2 + (size_t)NV * 32;
constexpr size_t OFF_HR_IV2 = OFF_HR_VV2 + (size_t)NV * 32;
constexpr size_t OFF_HL_VI2 = OFF_HR_IV2 + (size_t)NV * 32;
constexpr size_t OFF_HL_IV2 = OFF_HL_VI2 + (size_t)NV * 32;
constexpr size_t OFF_HR_VI2 = OFF_HL_IV2 + (size_t)NR * 32;
constexpr size_t L2_END     = OFF_HR_VI2 + (size_t)NR * 32;
static_assert(L2_END <= OFF_V1, "layer-2 overlay must not clobber v1/r1");

// ---------------- CSR build ----------------
__global__ __launch_bounds__(256) void k_count3(
    const int* __restrict__ dvv, const int* __restrict__ div_, const int* __restrict__ dvi,
    int* __restrict__ cvv, int* __restrict__ civ, int* __restrict__ cvi) {
  int t = blockIdx.x * blockDim.x + threadIdx.x;
  if (t < EVV) atomicAdd(&cvv[dvv[t]], 1);
  else if (t < EVV + EIV) atomicAdd(&civ[div_[t - EVV]], 1);
  else if (t < ETOT) atomicAdd(&cvi[dvi[t - EVV - EIV]], 1);
}

__global__ __launch_bounds__(1024) void k_scan3(
    const int* c0, int* p0, int n0,
    const int* c1, int* p1, int n1,
    const int* c2, int* p2, int n2) {
  const int* cnt = blockIdx.x == 0 ? c0 : blockIdx.x == 1 ? c1 : c2;
  int* ptr = blockIdx.x == 0 ? p0 : blockIdx.x == 1 ? p1 : p2;
  int n = blockIdx.x == 0 ? n0 : blockIdx.x == 1 ? n1 : n2;
  __shared__ int tsum[1024];
  int t = threadIdx.x;
  int per = (n + 1023) >> 10;
  int base = t * per;
  int s = 0;
  for (int i = 0; i < per; i++) { int idx = base + i; if (idx < n) s += cnt[idx]; }
  tsum[t] = s;
  for (int off = 1; off < 1024; off <<= 1) {
    __syncthreads();
    int v = (t >= off) ? tsum[t - off] : 0;
    __syncthreads();
    tsum[t] += v;
  }
  __syncthreads();
  int run = tsum[t] - s;
  for (int i = 0; i < per; i++) {
    int idx = base + i;
    if (idx < n) { ptr[idx] = run; run += cnt[idx]; }
  }
  if (t == 1023) ptr[n] = tsum[1023];
}

__global__ __launch_bounds__(256) void k_fill3(
    const int* __restrict__ svv, const int* __restrict__ dvv, const float* __restrict__ eavv,
    const int* __restrict__ siv, const int* __restrict__ div_, const float* __restrict__ eaiv,
    const int* __restrict__ svi, const int* __restrict__ dvi, const float* __restrict__ eavi,
    const int* __restrict__ pvv, int* __restrict__ uvv, Edge* __restrict__ evv,
    const int* __restrict__ piv, int* __restrict__ uiv, Edge* __restrict__ eiv,
    const int* __restrict__ pvi, int* __restrict__ uvi, Edge* __restrict__ evi) {
  int t = blockIdx.x * blockDim.x + threadIdx.x;
  if (t < EVV) {
    int e = t, d = dvv[e];
    int idx = pvv[d] + atomicAdd(&uvv[d], 1);
    Edge ed; ed.s = svv[e]; ed.ea = __floats2half2_rn(eavv[2 * e], eavv[2 * e + 1]);
    evv[idx] = ed;
  } else if (t < EVV + EIV) {
    int e = t - EVV, d = div_[e];
    int idx = piv[d] + atomicAdd(&uiv[d], 1);
    Edge ed; ed.s = siv[e]; ed.ea = __floats2half2_rn(eaiv[2 * e], eaiv[2 * e + 1]);
    eiv[idx] = ed;
  } else if (t < ETOT) {
    int e = t - EVV - EIV, d = dvi[e];
    int idx = pvi[d] + atomicAdd(&uvi[d], 1);
    Edge ed; ed.s = svi[e]; ed.ea = __floats2half2_rn(eavi[2 * e], eavi[2 * e + 1]);
    evi[idx] = ed;
  }
}

// self-loop mean ea from CSR-ordered vv edge segments (no atomics)
__global__ __launch_bounds__(256) void k_mean_seg(const int* __restrict__ ptr,
    const Edge* __restrict__ ed, float* __restrict__ mean, int n) {
  int d = blockIdx.x * blockDim.x + threadIdx.x;
  if (d >= n) return;
  int b = ptr[d], e = ptr[d + 1];
  float sx = 0.f, sy = 0.f;
  for (int i = b; i < e; i++) {
    float2 f = __half22float2(ed[i].ea);
    sx += f.x; sy += f.y;
  }
  float dg = fmaxf((float)(e - b), 1.f);
  mean[2 * d] = sx / dg;
  mean[2 * d + 1] = sy / dg;
}

// ---------------- layer-1 GEMM: K in {16,8}, C=128, half head-interleaved output ----------------
template<int K, int NW>
__global__ __launch_bounds__(256) void k_gemm1(const float* __restrict__ X,
    const float* __restrict__ W0, const float* __restrict__ W1,
    const float* __restrict__ W2, const float* __restrict__ W3,
    __half* __restrict__ Y0, __half* __restrict__ Y1,
    __half* __restrict__ Y2, __half* __restrict__ Y3, int n) {
  constexpr int ROWS = 32;
  __shared__ float xs[ROWS][K];
  int r0 = blockIdx.x * ROWS;
  int tid = threadIdx.x;
  int col = tid & 127, grp = tid >> 7;
  for (int i = tid; i < ROWS * K; i += 256) {
    int gi = r0 * K + i;
    ((float*)xs)[i] = (gi < n * K) ? X[gi] : 0.f;
  }
  __syncthreads();
  const float* Ws[4] = {W0, W1, W2, W3};
  __half* Ys[4] = {Y0, Y1, Y2, Y3};
  int oidx = ((col & 63) << 1) + (col >> 6);   // head-interleaved half index
  for (int rep = 0; rep < NW / 2; rep++) {
    int wi = grp + rep * 2;
    const float* __restrict__ W = Ws[wi];
    __half* __restrict__ Y = Ys[wi];
    float acc[ROWS];
#pragma unroll
    for (int r = 0; r < ROWS; r++) acc[r] = 0.f;
    for (int k4 = 0; k4 < K / 4; k4++) {
      float w0 = W[(4 * k4 + 0) * 128 + col];
      float w1 = W[(4 * k4 + 1) * 128 + col];
      float w2 = W[(4 * k4 + 2) * 128 + col];
      float w3 = W[(4 * k4 + 3) * 128 + col];
#pragma unroll
      for (int r = 0; r < ROWS; r++) {
        float4 x4 = *(const float4*)&xs[r][4 * k4];
        acc[r] = fmaf(x4.x, w0, acc[r]);
        acc[r] = fmaf(x4.y, w1, acc[r]);
        acc[r] = fmaf(x4.z, w2, acc[r]);
        acc[r] = fmaf(x4.w, w3, acc[r]);
      }
    }
    for (int r = 0; r < ROWS; r++)
      if (r0 + r < n) Y[(size_t)(r0 + r) * 128 + oidx] = __float2half(acc[r]);
  }
}

// ---------------- layer-2 GEMM: half X, K=128, C=64, half output ----------------
template<int NW>
__global__ __launch_bounds__(64 * NW) void k_gemm2(const __half* __restrict__ X,
    const float* __restrict__ W0, const float* __restrict__ W1,
    const float* __restrict__ W2, const float* __restrict__ W3,
    __half* __restrict__ Y0, __half* __restrict__ Y1,
    __half* __restrict__ Y2, __half* __restrict__ Y3, int n) {
  constexpr int ROWS = 32, K = 128;
  __shared__ float xs[ROWS][K];
  int r0 = blockIdx.x * ROWS;
  int tid = threadIdx.x;
  const __half2* X2 = (const __half2*)X;
  for (int i = tid; i < ROWS * K / 2; i += 64 * NW) {
    int gi = r0 * (K / 2) + i;
    float2 f = (gi < n * (K / 2)) ? __half22float2(X2[gi]) : make_float2(0.f, 0.f);
    ((float*)xs)[2 * i] = f.x;
    ((float*)xs)[2 * i + 1] = f.y;
  }
  __syncthreads();
  int lane = tid & 63, wv = tid >> 6;
  const float* Ws[4] = {W0, W1, W2, W3};
  __half* Ys[4] = {Y0, Y1, Y2, Y3};
  const float* __restrict__ W = Ws[wv];
  __half* __restrict__ Y = Ys[wv];
  float acc[ROWS];
#pragma unroll
  for (int r = 0; r < ROWS; r++) acc[r] = 0.f;
  for (int k4 = 0; k4 < K / 4; k4++) {
    float w0 = W[(4 * k4 + 0) * 64 + lane];
    float w1 = W[(4 * k4 + 1) * 64 + lane];
    float w2 = W[(4 * k4 + 2) * 64 + lane];
    float w3 = W[(4 * k4 + 3) * 64 + lane];
#pragma unroll
    for (int r = 0; r < ROWS; r++) {
      float4 x4 = *(const float4*)&xs[r][4 * k4];
      acc[r] = fmaf(x4.x, w0, acc[r]);
      acc[r] = fmaf(x4.y, w1, acc[r]);
      acc[r] = fmaf(x4.z, w2, acc[r]);
      acc[r] = fmaf(x4.w, w3, acc[r]);
    }
  }
  for (int r = 0; r < ROWS; r++)
    if (r0 + r < n) Y[(size_t)(r0 + r) * 64 + lane] = __float2half(acc[r]);
}

// ---------------- fused GATv2 aggregation (fp16 tables) ----------------
__device__ __forceinline__ void gat2(int d, int lane, int wv, int nw,
    bool self_loop, const float* __restrict__ mean_ea,
    const int* __restrict__ ptr, const Edge* __restrict__ ed,
    const __half2* __restrict__ hl, const __half2* __restrict__ hr,
    const float* __restrict__ We, const float* __restrict__ att,
    float* acc, float* den) {
  float2 hrc = __half22float2(hr[(size_t)d * 64 + lane]);
  float att0 = att[lane], att1 = att[64 + lane];
  float we00 = We[lane], we01 = We[64 + lane];
  float we10 = We[128 + lane], we11 = We[192 + lane];
  auto body = [&](int s, float e0, float e1) {
    float2 hlv = __half22float2(hl[(size_t)s * 64 + lane]);
    float g0 = hlv.x + hrc.x + e0 * we00 + e1 * we10;
    float g1 = hlv.y + hrc.y + e0 * we01 + e1 * we11;
    g0 = g0 > 0.f ? g0 : 0.2f * g0;
    g1 = g1 > 0.f ? g1 : 0.2f * g1;
    float l0 = g0 * att0, l1 = g1 * att1;
#pragma unroll
    for (int o = 32; o; o >>= 1) { l0 += __shfl_xor(l0, o); l1 += __shfl_xor(l1, o); }
    float ex0 = __expf(l0), ex1 = __expf(l1);
    acc[0] += ex0 * hlv.x; den[0] += ex0;
    acc[1] += ex1 * hlv.y; den[1] += ex1;
  };
  int b = ptr[d], en = ptr[d + 1];
  for (int i = b + wv; i < en; i += nw) {
    Edge e = ed[i];
    float2 ea = __half22float2(e.ea);
    body(e.s, ea.x, ea.y);
  }
  if (self_loop && wv == 0) body(d, mean_ea[2 * d], mean_ea[2 * d + 1]);
}

__device__ __forceinline__ void gat1(int d, int lane, int wv, int nw,
    bool self_loop, const float* __restrict__ mean_ea,
    const int* __restrict__ ptr, const Edge* __restrict__ ed,
    const __half* __restrict__ hl, const __half* __restrict__ hr,
    const float* __restrict__ We, const float* __restrict__ att,
    float& acc, float& den) {
  float hrc = __half2float(hr[(size_t)d * 64 + lane]);
  float attc = att[lane];
  float we0 = We[lane], we1 = We[64 + lane];
  auto body = [&](int s, float e0, float e1) {
    float hlv = __half2float(hl[(size_t)s * 64 + lane]);
    float g = hlv + hrc + e0 * we0 + e1 * we1;
    g = g > 0.f ? g : 0.2f * g;
    float l = g * attc;
#pragma unroll
    for (int o = 32; o; o >>= 1) l += __shfl_xor(l, o);
    float ex = __expf(l);
    acc += ex * hlv; den += ex;
  };
  int b = ptr[d], en = ptr[d + 1];
  for (int i = b + wv; i < en; i += nw) {
    Edge e = ed[i];
    float2 ea = __half22float2(e.ea);
    body(e.s, ea.x, ea.y);
  }
  if (self_loop && wv == 0) body(d, mean_ea[2 * d], mean_ea[2 * d + 1]);
}

// layer-1 merged: blocks [0,VB) = veh (wave per dst), [VB,VB+NR) = rsu (block per dst)
__global__ __launch_bounds__(256) void k_gat_l1(
    const int* ptr_vv, const Edge* e_vv, const float* mean_ea,
    const __half2* hl_vv, const __half2* hr_vv, const float* We_vv, const float* att_vv,
    const int* ptr_iv, const Edge* e_iv,
    const __half2* hl_iv, const __half2* hr_iv, const float* We_iv, const float* att_iv,
    const int* ptr_vi, const Edge* e_vi,
    const __half2* hl_vi, const __half2* hr_vi, const float* We_vi, const float* att_vi,
    const float* b_vv, const float* b_iv, const float* b_vi,
    __half* __restrict__ v1, __half* __restrict__ r1) {
  __shared__ float pa[4][2][64], pd[4][2][64];
  int lane = threadIdx.x & 63, wv = threadIdx.x >> 6;
  if (blockIdx.x < VB) {
    int w = blockIdx.x * 4 + wv;
    if (w >= NV) return;
    float oc0, oc1;
    {
      float acc[2] = {0.f, 0.f}, den[2] = {0.f, 0.f};
      gat2(w, lane, 0, 1, true, mean_ea, ptr_vv, e_vv, hl_vv, hr_vv, We_vv, att_vv, acc, den);
      oc0 = acc[0] / (den[0] + 1e-16f); oc1 = acc[1] / (den[1] + 1e-16f);
    }
    {
      float acc[2] = {0.f, 0.f}, den[2] = {0.f, 0.f};
      gat2(w, lane, 0, 1, false, nullptr, ptr_iv, e_iv, hl_iv, hr_iv, We_iv, att_iv, acc, den);
      oc0 += acc[0] / (den[0] + 1e-16f); oc1 += acc[1] / (den[1] + 1e-16f);
    }
    float x0 = oc0 + b_vv[lane] + b_iv[lane];
    float x1 = oc1 + b_vv[64 + lane] + b_iv[64 + lane];
    x0 = x0 > 0.f ? x0 : __expf(x0) - 1.f;
    x1 = x1 > 0.f ? x1 : __expf(x1) - 1.f;
    v1[(size_t)w * 128 + lane]      = __float2half(x0);
    v1[(size_t)w * 128 + 64 + lane] = __float2half(x1);
  } else {
    int d = blockIdx.x - VB;
    float acc[2] = {0.f, 0.f}, den[2] = {0.f, 0.f};
    gat2(d, lane, wv, 4, false, nullptr, ptr_vi, e_vi, hl_vi, hr_vi, We_vi, att_vi, acc, den);
    pa[wv][0][lane] = acc[0]; pa[wv][1][lane] = acc[1];
    pd[wv][0][lane] = den[0]; pd[wv][1][lane] = den[1];
    __syncthreads();
    if (wv == 0) {
#pragma unroll
      for (int j = 1; j < 4; j++) {
        acc[0] += pa[j][0][lane]; acc[1] += pa[j][1][lane];
        den[0] += pd[j][0][lane]; den[1] += pd[j][1][lane];
      }
      float x0 = acc[0] / (den[0] + 1e-16f) + b_vi[lane];
      float x1 = acc[1] / (den[1] + 1e-16f) + b_vi[64 + lane];
      x0 = x0 > 0.f ? x0 : __expf(x0) - 1.f;
      x1 = x1 > 0.f ? x1 : __expf(x1) - 1.f;
      r1[(size_t)d * 128 + lane]      = __float2half(x0);
      r1[(size_t)d * 128 + 64 + lane] = __float2half(x1);
    }
  }
}

__device__ __forceinline__ void ln_write(int lane, float x,
    const float* __restrict__ g, const float* __restrict__ beta,
    float* __restrict__ out) {
  float s = x;
#pragma unroll
  for (int o = 32; o; o >>= 1) s += __shfl_xor(s, o);
  float mu = s * (1.f / 64.f);
  float dx = x - mu;
  float vs = dx * dx;
#pragma unroll
  for (int o = 32; o; o >>= 1) vs += __shfl_xor(vs, o);
  out[lane] = dx * rsqrtf(vs * (1.f / 64.f) + 1e-5f) * g[lane] + beta[lane];
}

// layer-2 merged: veh rows -> out[0..NV), rsu rows -> out[NV..NV+NR)
__global__ __launch_bounds__(256) void k_gat_l2(
    const int* ptr_vv, const Edge* e_vv, const float* mean_ea,
    const __half* hl_vv, const __half* hr_vv, const float* We_vv, const float* att_vv,
    const int* ptr_iv, const Edge* e_iv,
    const __half* hl_iv, const __half* hr_iv, const float* We_iv, const float* att_iv,
    const int* ptr_vi, const Edge* e_vi,
    const __half* hl_vi, const __half* hr_vi, const float* We_vi, const float* att_vi,
    const float* b_vv, const float* b_iv, const float* b_vi,
    const float* ln_vg, const float* ln_vb, const float* ln_rg, const float* ln_rb,
    float* __restrict__ out) {
  __shared__ float pa[4][64], pd[4][64];
  int lane = threadIdx.x & 63, wv = threadIdx.x >> 6;
  if (blockIdx.x < VB) {
    int w = blockIdx.x * 4 + wv;
    if (w >= NV) return;
    float oc;
    {
      float acc = 0.f, den = 0.f;
      gat1(w, lane, 0, 1, true, mean_ea, ptr_vv, e_vv, hl_vv, hr_vv, We_vv, att_vv, acc, den);
      oc = acc / (den + 1e-16f);
    }
    {
      float acc = 0.f, den = 0.f;
      gat1(w, lane, 0, 1, false, nullptr, ptr_iv, e_iv, hl_iv, hr_iv, We_iv, att_iv, acc, den);
      oc += acc / (den + 1e-16f);
    }
    float x = oc + b_vv[lane] + b_iv[lane];
    ln_write(lane, x, ln_vg, ln_vb, out + (size_t)w * 64);
  } else {
    int d = blockIdx.x - VB;
    float acc = 0.f, den = 0.f;
    gat1(d, lane, wv, 4, false, nullptr, ptr_vi, e_vi, hl_vi, hr_vi, We_vi, att_vi, acc, den);
    pa[wv][lane] = acc; pd[wv][lane] = den;
    __syncthreads();
    if (wv == 0) {
#pragma unroll
      for (int j = 1; j < 4; j++) { acc += pa[j][lane]; den += pd[j][lane]; }
      float x = acc / (den + 1e-16f) + b_vi[lane];
      ln_write(lane, x, ln_rg, ln_rb, out + (size_t)(NV + d) * 64);
    }
  }
}

// ---------------- launch ----------------
extern "C" void kernel_launch(void* const* d_in, const int* in_sizes, int n_in,
                              void* d_out, int out_size, void* d_ws, size_t ws_size,
                              hipStream_t stream) {
  const float* x_veh  = (const float*)d_in[0];
  const float* x_rsu  = (const float*)d_in[1];
  const float* ea_vv  = (const float*)d_in[2];
  const float* ea_vi  = (const float*)d_in[3];
  const float* ea_iv  = (const float*)d_in[4];
  const int*   src_vv = (const int*)d_in[5];
  const int*   dst_vv = (const int*)d_in[6];
  const int*   src_vi = (const int*)d_in[7];
  const int*   dst_vi = (const int*)d_in[8];
  const int*   src_iv = (const int*)d_in[9];
  const int*   dst_iv = (const int*)d_in[10];
  const float* Wl_vv1 = (const float*)d_in[11];
  const float* Wr_vv1 = (const float*)d_in[12];
  const float* We_vv1 = (const float*)d_in[13];
  const float* att_vv1= (const float*)d_in[14];
  const float* b_vv1  = (const float*)d_in[15];
  const float* Wl_vi1 = (const float*)d_in[16];
  const float* Wr_vi1 = (const float*)d_in[17];
  const float* We_vi1 = (const float*)d_in[18];
  const float* att_vi1= (const float*)d_in[19];
  const float* b_vi1  = (const float*)d_in[20];
  const float* Wl_iv1 = (const float*)d_in[21];
  const float* Wr_iv1 = (const float*)d_in[22];
  const float* We_iv1 = (const float*)d_in[23];
  const float* att_iv1= (const float*)d_in[24];
  const float* b_iv1  = (const float*)d_in[25];
  const float* Wl_vv2 = (const float*)d_in[26];
  const float* Wr_vv2 = (const float*)d_in[27];
  const float* We_vv2 = (const float*)d_in[28];
  const float* att_vv2= (const float*)d_in[29];
  const float* b_vv2  = (const float*)d_in[30];
  const float* Wl_vi2 = (const float*)d_in[31];
  const float* Wr_vi2 = (const float*)d_in[32];
  const float* We_vi2 = (const float*)d_in[33];
  const float* att_vi2= (const float*)d_in[34];
  const float* b_vi2  = (const float*)d_in[35];
  const float* Wl_iv2 = (const float*)d_in[36];
  const float* Wr_iv2 = (const float*)d_in[37];
  const float* We_iv2 = (const float*)d_in[38];
  const float* att_iv2= (const float*)d_in[39];
  const float* b_iv2  = (const float*)d_in[40];
  const float* ln_vg  = (const float*)d_in[41];
  const float* ln_vb  = (const float*)d_in[42];
  const float* ln_rg  = (const float*)d_in[43];
  const float* ln_rb  = (const float*)d_in[44];

  float* ws  = (float*)d_ws;
  float* out = (float*)d_out;

  int* cnt_vv = (int*)(ws + OFF_CNT_VV); int* cur_vv = (int*)(ws + OFF_CUR_VV);
  int* cnt_iv = (int*)(ws + OFF_CNT_IV); int* cur_iv = (int*)(ws + OFF_CUR_IV);
  int* cnt_vi = (int*)(ws + OFF_CNT_VI); int* cur_vi = (int*)(ws + OFF_CUR_VI);
  int* ptr_vv = (int*)(ws + OFF_PTR_VV);
  int* ptr_iv = (int*)(ws + OFF_PTR_IV);
  int* ptr_vi = (int*)(ws + OFF_PTR_VI);
  float* mean = ws + OFF_MEAN;
  Edge* e_vv = (Edge*)(ws + OFF_E_VV);
  Edge* e_iv = (Edge*)(ws + OFF_E_IV);
  Edge* e_vi = (Edge*)(ws + OFF_E_VI);

  __half* hl_vv1 = (__half*)(ws + OFF_HL_VV1);
  __half* hr_vv1 = (__half*)(ws + OFF_HR_VV1);
  __half* hr_iv1 = (__half*)(ws + OFF_HR_IV1);
  __half* hl_vi1 = (__half*)(ws + OFF_HL_VI1);
  __half* hl_iv1 = (__half*)(ws + OFF_HL_IV1);
  __half* hr_vi1 = (__half*)(ws + OFF_HR_VI1);
  __half* v1 = (__half*)(ws + OFF_V1);
  __half* r1 = (__half*)(ws + OFF_R1);
  __half* hl_vv2 = (__half*)(ws + OFF_HL_VV2);
  __half* hr_vv2 = (__half*)(ws + OFF_HR_VV2);
  __half* hr_iv2 = (__half*)(ws + OFF_HR_IV2);
  __half* hl_vi2 = (__half*)(ws + OFF_HL_VI2);
  __half* hl_iv2 = (__half*)(ws + OFF_HL_IV2);
  __half* hr_vi2 = (__half*)(ws + OFF_HR_VI2);

  hipMemsetAsync(ws, 0, ZERO_END * sizeof(float), stream);

  k_count3<<<(ETOT + 255) / 256, 256, 0, stream>>>(dst_vv, dst_iv, dst_vi,
      cnt_vv, cnt_iv, cnt_vi);
  k_scan3<<<3, 1024, 0, stream>>>(cnt_vv, ptr_vv, NV, cnt_iv, ptr_iv, NV, cnt_vi, ptr_vi, NR);
  k_fill3<<<(ETOT + 255) / 256, 256, 0, stream>>>(
      src_vv, dst_vv, ea_vv, src_iv, dst_iv, ea_iv, src_vi, dst_vi, ea_vi,
      ptr_vv, cur_vv, e_vv, ptr_iv, cur_iv, e_iv, ptr_vi, cur_vi, e_vi);
  k_mean_seg<<<(NV + 255) / 256, 256, 0, stream>>>(ptr_vv, e_vv, mean, NV);

  // layer-1 dense transforms (head-interleaved fp16 outputs)
  k_gemm1<16, 4><<<(NV + 31) / 32, 256, 0, stream>>>(x_veh,
      Wl_vv1, Wr_vv1, Wr_iv1, Wl_vi1, hl_vv1, hr_vv1, hr_iv1, hl_vi1, NV);
  k_gemm1<8, 2><<<(NR + 31) / 32, 256, 0, stream>>>(x_rsu,
      Wl_iv1, Wr_vi1, nullptr, nullptr, hl_iv1, hr_vi1, nullptr, nullptr, NR);

  // layer-1 fused aggregation (+rsu blocks appended)
  k_gat_l1<<<VB + NR, 256, 0, stream>>>(
      ptr_vv, e_vv, mean,
      (const __half2*)hl_vv1, (const __half2*)hr_vv1, We_vv1, att_vv1,
      ptr_iv, e_iv, (const __half2*)hl_iv1, (const __half2*)hr_iv1, We_iv1, att_iv1,
      ptr_vi, e_vi, (const __half2*)hl_vi1, (const __half2*)hr_vi1, We_vi1, att_vi1,
      b_vv1, b_iv1, b_vi1, v1, r1);

  // layer-2 dense transforms
  k_gemm2<4><<<(NV + 31) / 32, 256, 0, stream>>>(v1,
      Wl_vv2, Wr_vv2, Wr_iv2, Wl_vi2, hl_vv2, hr_vv2, hr_iv2, hl_vi2, NV);
  k_gemm2<2><<<(NR + 31) / 32, 128, 0, stream>>>(r1,
      Wl_iv2, Wr_vi2, nullptr, nullptr, hl_iv2, hr_vi2, nullptr, nullptr, NR);

  // layer-2 fused aggregation + LayerNorm -> out
  k_gat_l2<<<VB + NR, 256, 0, stream>>>(
      ptr_vv, e_vv, mean,
      hl_vv2, hr_vv2, We_vv2, att_vv2,
      ptr_iv, e_iv, hl_iv2, hr_iv2, We_iv2, att_iv2,
      ptr_vi, e_vi, hl_vi2, hr_vi2, We_vi2, att_vi2,
      b_vv2, b_iv2, b_vi2, ln_vg, ln_vb, ln_rg, ln_rb, out);
  (void)in_sizes; (void)n_in; (void)out_size; (void)ws_size;
}

// Round 5
// 448.215 us; speedup vs baseline: 2.6803x; 1.1464x over previous
//
#include <hip/hip_runtime.h>
#include <hip/hip_fp16.h>

// ---------------- problem constants ----------------
constexpr int NV = 30000, NR = 1000;
constexpr int EVV = 400000, EVI = 120000, EIV = 120000;
constexpr int ETOT = EVV + EIV + EVI;
constexpr int VB = (NV + 3) / 4;   // veh blocks in merged gat kernels

struct __align__(8) Edge { int s; __half2 ea; };

// ---------------- workspace layout (float units) ----------------
constexpr size_t OFF_CNT_VV = 0;                       // NV
constexpr size_t OFF_CUR_VV = OFF_CNT_VV + NV;
constexpr size_t OFF_CNT_IV = OFF_CUR_VV + NV;
constexpr size_t OFF_CUR_IV = OFF_CNT_IV + NV;
constexpr size_t OFF_CNT_VI = OFF_CUR_IV + NV;
constexpr size_t OFF_CUR_VI = OFF_CNT_VI + NR;
constexpr size_t ZERO_END   = OFF_CUR_VI + NR;         // 122000
constexpr size_t OFF_PTR_VV = ZERO_END;                // NV+2
constexpr size_t OFF_PTR_IV = OFF_PTR_VV + NV + 2;
constexpr size_t OFF_PTR_VI = OFF_PTR_IV + NV + 2;
constexpr size_t OFF_MEAN   = OFF_PTR_VI + NR + 2;     // 2*NV
constexpr size_t OFF_E_VV   = OFF_MEAN + (size_t)NV * 2;   // Edge = 2 floats
constexpr size_t OFF_E_IV   = OFF_E_VV + (size_t)EVV * 2;
constexpr size_t OFF_E_VI   = OFF_E_IV + (size_t)EIV * 2;
constexpr size_t OFF_H      = (OFF_E_VI + (size_t)EVI * 2 + 3) & ~(size_t)3;  // 16B align
// layer-1 tables: 128 halves/row = 64 float-units/row (head-interleaved: pos p = c*2+h)
constexpr size_t OFF_HL_VV1 = OFF_H;
constexpr size_t OFF_HR_VV1 = OFF_HL_VV1 + (size_t)NV * 64;
constexpr size_t OFF_HR_IV1 = OFF_HR_VV1 + (size_t)NV * 64;
constexpr size_t OFF_HL_VI1 = OFF_HR_IV1 + (size_t)NV * 64;
constexpr size_t OFF_HL_IV1 = OFF_HL_VI1 + (size_t)NV * 64;
constexpr size_t OFF_HR_VI1 = OFF_HL_IV1 + (size_t)NR * 64;
constexpr size_t L1_END     = OFF_HR_VI1 + (size_t)NR * 64;
// v1/r1: fp16 standard channel order (128 halves/row)
constexpr size_t OFF_V1     = L1_END;
constexpr size_t OFF_R1     = OFF_V1 + (size_t)NV * 64;
constexpr size_t WS_END     = OFF_R1 + (size_t)NR * 64;
// layer-2 tables overlay layer-1 region: 64 halves/row (standard order)
constexpr size_t OFF_HL_VV2 = OFF_H;
constexpr size_t OFF_HR_VV2 = OFF_HL_VV2 + (size_t)NV * 32;
constexpr size_t OFF_HR_IV2 = OFF_HR_VV2 + (size_t)NV * 32;
constexpr size_t OFF_HL_VI2 = OFF_HR_IV2 + (size_t)NV * 32;
constexpr size_t OFF_HL_IV2 = OFF_HL_VI2 + (size_t)NV * 32;
constexpr size_t OFF_HR_VI2 = OFF_HL_IV2 + (size_t)NR * 32;
constexpr size_t L2_END     = OFF_HR_VI2 + (size_t)NR * 32;
static_assert(L2_END <= OFF_V1, "layer-2 overlay must not clobber v1/r1");

// ---------------- CSR build ----------------
__global__ __launch_bounds__(256) void k_count3(
    const int* __restrict__ dvv, const int* __restrict__ div_, const int* __restrict__ dvi,
    int* __restrict__ cvv, int* __restrict__ civ, int* __restrict__ cvi) {
  int t = blockIdx.x * blockDim.x + threadIdx.x;
  if (t < EVV) atomicAdd(&cvv[dvv[t]], 1);
  else if (t < EVV + EIV) atomicAdd(&civ[div_[t - EVV]], 1);
  else if (t < ETOT) atomicAdd(&cvi[dvi[t - EVV - EIV]], 1);
}

__global__ __launch_bounds__(1024) void k_scan3(
    const int* c0, int* p0, int n0,
    const int* c1, int* p1, int n1,
    const int* c2, int* p2, int n2) {
  const int* cnt = blockIdx.x == 0 ? c0 : blockIdx.x == 1 ? c1 : c2;
  int* ptr = blockIdx.x == 0 ? p0 : blockIdx.x == 1 ? p1 : p2;
  int n = blockIdx.x == 0 ? n0 : blockIdx.x == 1 ? n1 : n2;
  __shared__ int tsum[1024];
  int t = threadIdx.x;
  int per = (n + 1023) >> 10;
  int base = t * per;
  int s = 0;
  for (int i = 0; i < per; i++) { int idx = base + i; if (idx < n) s += cnt[idx]; }
  tsum[t] = s;
  for (int off = 1; off < 1024; off <<= 1) {
    __syncthreads();
    int v = (t >= off) ? tsum[t - off] : 0;
    __syncthreads();
    tsum[t] += v;
  }
  __syncthreads();
  int run = tsum[t] - s;
  for (int i = 0; i < per; i++) {
    int idx = base + i;
    if (idx < n) { ptr[idx] = run; run += cnt[idx]; }
  }
  if (t == 1023) ptr[n] = tsum[1023];
}

__global__ __launch_bounds__(256) void k_fill3(
    const int* __restrict__ svv, const int* __restrict__ dvv, const float* __restrict__ eavv,
    const int* __restrict__ siv, const int* __restrict__ div_, const float* __restrict__ eaiv,
    const int* __restrict__ svi, const int* __restrict__ dvi, const float* __restrict__ eavi,
    const int* __restrict__ pvv, int* __restrict__ uvv, Edge* __restrict__ evv,
    const int* __restrict__ piv, int* __restrict__ uiv, Edge* __restrict__ eiv,
    const int* __restrict__ pvi, int* __restrict__ uvi, Edge* __restrict__ evi) {
  int t = blockIdx.x * blockDim.x + threadIdx.x;
  if (t < EVV) {
    int e = t, d = dvv[e];
    int idx = pvv[d] + atomicAdd(&uvv[d], 1);
    Edge ed; ed.s = svv[e]; ed.ea = __floats2half2_rn(eavv[2 * e], eavv[2 * e + 1]);
    evv[idx] = ed;
  } else if (t < EVV + EIV) {
    int e = t - EVV, d = div_[e];
    int idx = piv[d] + atomicAdd(&uiv[d], 1);
    Edge ed; ed.s = siv[e]; ed.ea = __floats2half2_rn(eaiv[2 * e], eaiv[2 * e + 1]);
    eiv[idx] = ed;
  } else if (t < ETOT) {
    int e = t - EVV - EIV, d = dvi[e];
    int idx = pvi[d] + atomicAdd(&uvi[d], 1);
    Edge ed; ed.s = svi[e]; ed.ea = __floats2half2_rn(eavi[2 * e], eavi[2 * e + 1]);
    evi[idx] = ed;
  }
}

// self-loop mean ea from CSR-ordered vv edge segments
__global__ __launch_bounds__(256) void k_mean_seg(const int* __restrict__ ptr,
    const Edge* __restrict__ ed, float* __restrict__ mean, int n) {
  int d = blockIdx.x * blockDim.x + threadIdx.x;
  if (d >= n) return;
  int b = ptr[d], e = ptr[d + 1];
  float sx = 0.f, sy = 0.f;
  for (int i = b; i < e; i++) {
    float2 f = __half22float2(ed[i].ea);
    sx += f.x; sy += f.y;
  }
  float dg = fmaxf((float)(e - b), 1.f);
  mean[2 * d] = sx / dg;
  mean[2 * d + 1] = sy / dg;
}

// ---------------- layer-1 GEMM: K in {16,8}, C=128, half head-interleaved output ----------------
template<int K, int NW>
__global__ __launch_bounds__(256) void k_gemm1(const float* __restrict__ X,
    const float* __restrict__ W0, const float* __restrict__ W1,
    const float* __restrict__ W2, const float* __restrict__ W3,
    __half* __restrict__ Y0, __half* __restrict__ Y1,
    __half* __restrict__ Y2, __half* __restrict__ Y3, int n) {
  constexpr int ROWS = 32;
  __shared__ float xs[ROWS][K];
  int r0 = blockIdx.x * ROWS;
  int tid = threadIdx.x;
  int col = tid & 127, grp = tid >> 7;
  for (int i = tid; i < ROWS * K; i += 256) {
    int gi = r0 * K + i;
    ((float*)xs)[i] = (gi < n * K) ? X[gi] : 0.f;
  }
  __syncthreads();
  const float* Ws[4] = {W0, W1, W2, W3};
  __half* Ys[4] = {Y0, Y1, Y2, Y3};
  int oidx = ((col & 63) << 1) + (col >> 6);   // head-interleaved half index
  for (int rep = 0; rep < NW / 2; rep++) {
    int wi = grp + rep * 2;
    const float* __restrict__ W = Ws[wi];
    __half* __restrict__ Y = Ys[wi];
    float acc[ROWS];
#pragma unroll
    for (int r = 0; r < ROWS; r++) acc[r] = 0.f;
    for (int k4 = 0; k4 < K / 4; k4++) {
      float w0 = W[(4 * k4 + 0) * 128 + col];
      float w1 = W[(4 * k4 + 1) * 128 + col];
      float w2 = W[(4 * k4 + 2) * 128 + col];
      float w3 = W[(4 * k4 + 3) * 128 + col];
#pragma unroll
      for (int r = 0; r < ROWS; r++) {
        float4 x4 = *(const float4*)&xs[r][4 * k4];
        acc[r] = fmaf(x4.x, w0, acc[r]);
        acc[r] = fmaf(x4.y, w1, acc[r]);
        acc[r] = fmaf(x4.z, w2, acc[r]);
        acc[r] = fmaf(x4.w, w3, acc[r]);
      }
    }
    for (int r = 0; r < ROWS; r++)
      if (r0 + r < n) Y[(size_t)(r0 + r) * 128 + oidx] = __float2half(acc[r]);
  }
}

// ---------------- layer-2 GEMM: half X, K=128, C=64, half output ----------------
template<int NW>
__global__ __launch_bounds__(64 * NW) void k_gemm2(const __half* __restrict__ X,
    const float* __restrict__ W0, const float* __restrict__ W1,
    const float* __restrict__ W2, const float* __restrict__ W3,
    __half* __restrict__ Y0, __half* __restrict__ Y1,
    __half* __restrict__ Y2, __half* __restrict__ Y3, int n) {
  constexpr int ROWS = 32, K = 128;
  __shared__ float xs[ROWS][K];
  int r0 = blockIdx.x * ROWS;
  int tid = threadIdx.x;
  const __half2* X2 = (const __half2*)X;
  for (int i = tid; i < ROWS * K / 2; i += 64 * NW) {
    int gi = r0 * (K / 2) + i;
    float2 f = (gi < n * (K / 2)) ? __half22float2(X2[gi]) : make_float2(0.f, 0.f);
    ((float*)xs)[2 * i] = f.x;
    ((float*)xs)[2 * i + 1] = f.y;
  }
  __syncthreads();
  int lane = tid & 63, wv = tid >> 6;
  const float* Ws[4] = {W0, W1, W2, W3};
  __half* Ys[4] = {Y0, Y1, Y2, Y3};
  const float* __restrict__ W = Ws[wv];
  __half* __restrict__ Y = Ys[wv];
  float acc[ROWS];
#pragma unroll
  for (int r = 0; r < ROWS; r++) acc[r] = 0.f;
  for (int k4 = 0; k4 < K / 4; k4++) {
    float w0 = W[(4 * k4 + 0) * 64 + lane];
    float w1 = W[(4 * k4 + 1) * 64 + lane];
    float w2 = W[(4 * k4 + 2) * 64 + lane];
    float w3 = W[(4 * k4 + 3) * 64 + lane];
#pragma unroll
    for (int r = 0; r < ROWS; r++) {
      float4 x4 = *(const float4*)&xs[r][4 * k4];
      acc[r] = fmaf(x4.x, w0, acc[r]);
      acc[r] = fmaf(x4.y, w1, acc[r]);
      acc[r] = fmaf(x4.z, w2, acc[r]);
      acc[r] = fmaf(x4.w, w3, acc[r]);
    }
  }
  for (int r = 0; r < ROWS; r++)
    if (r0 + r < n) Y[(size_t)(r0 + r) * 64 + lane] = __float2half(acc[r]);
}

// ---------------- transposed GATv2 aggregation ----------------
// lane = 16*eg + cg : 4 edges in flight per wave, each 16-lane group owns one
// edge; lane owns 4 channels/head. Logit reduce = 4-step butterfly within 16
// lanes; cross-group combine (xor 16,32) once per dst.

// layer-1: H=2, tables head-interleaved (pos p = c*2 + h), 8 halves/lane
template<bool SELF>
__device__ __forceinline__ void gatT2(int d, int eg, int cg, int wv, int nw,
    const float* __restrict__ mean_ea,
    const int* __restrict__ ptr, const Edge* __restrict__ ed,
    const __half* __restrict__ hl, const __half* __restrict__ hr,
    const float* __restrict__ We, const float* __restrict__ att,
    float* acc, float& den0, float& den1) {
  float hrc[8], av[8], w0[8], w1[8];
  {
    float4 r = *(const float4*)&hr[(size_t)d * 128 + cg * 8];
    const __half2* hp = (const __half2*)&r;
#pragma unroll
    for (int j = 0; j < 4; j++) {
      float2 f = __half22float2(hp[j]);
      hrc[2 * j] = f.x; hrc[2 * j + 1] = f.y;
    }
  }
#pragma unroll
  for (int j = 0; j < 8; j++) {
    int p = cg * 8 + j;
    int idx = (p & 1) * 64 + (p >> 1);
    av[j] = att[idx]; w0[j] = We[idx]; w1[j] = We[128 + idx];
  }
  int b = ptr[d], en = ptr[d + 1];
  int en_ext = en + (SELF ? 1 : 0);
  for (int base = b + wv * 4; base < en_ext; base += 4 * nw) {
    int p = base + eg;
    int s = 0; float e0 = 0.f, e1 = 0.f;
    bool valid = p < en_ext;
    if (p < en) {
      Edge e = ed[p]; s = e.s;
      float2 f = __half22float2(e.ea); e0 = f.x; e1 = f.y;
    } else if (SELF && p == en) {
      s = d; e0 = mean_ea[2 * d]; e1 = mean_ea[2 * d + 1];
    }
    float hlv[8];
    {
      float4 r = *(const float4*)&hl[(size_t)s * 128 + cg * 8];
      const __half2* hp = (const __half2*)&r;
#pragma unroll
      for (int j = 0; j < 4; j++) {
        float2 f = __half22float2(hp[j]);
        hlv[2 * j] = f.x; hlv[2 * j + 1] = f.y;
      }
    }
    float l0 = 0.f, l1 = 0.f;
#pragma unroll
    for (int j = 0; j < 8; j++) {
      float g = hlv[j] + hrc[j] + e0 * w0[j] + e1 * w1[j];
      g = g > 0.f ? g : 0.2f * g;
      float t = g * av[j];
      if (j & 1) l1 += t; else l0 += t;
    }
#pragma unroll
    for (int o = 1; o <= 8; o <<= 1) {
      l0 += __shfl_xor(l0, o);
      l1 += __shfl_xor(l1, o);
    }
    float ex0 = valid ? __expf(l0) : 0.f;
    float ex1 = valid ? __expf(l1) : 0.f;
#pragma unroll
    for (int j = 0; j < 8; j++)
      acc[j] = fmaf((j & 1) ? ex1 : ex0, hlv[j], acc[j]);
    den0 += ex0; den1 += ex1;
  }
#pragma unroll
  for (int o = 16; o <= 32; o <<= 1) {
#pragma unroll
    for (int j = 0; j < 8; j++) acc[j] += __shfl_xor(acc[j], o);
    den0 += __shfl_xor(den0, o);
    den1 += __shfl_xor(den1, o);
  }
}

// layer-2: H=1, standard 64-half rows, 4 halves/lane
template<bool SELF>
__device__ __forceinline__ void gatT1(int d, int eg, int cg, int wv, int nw,
    const float* __restrict__ mean_ea,
    const int* __restrict__ ptr, const Edge* __restrict__ ed,
    const __half* __restrict__ hl, const __half* __restrict__ hr,
    const float* __restrict__ We, const float* __restrict__ att,
    float* acc, float& den) {
  float hrc[4], av[4], w0[4], w1[4];
  {
    float2 r = *(const float2*)&hr[(size_t)d * 64 + cg * 4];
    const __half2* hp = (const __half2*)&r;
    float2 f0 = __half22float2(hp[0]), f1 = __half22float2(hp[1]);
    hrc[0] = f0.x; hrc[1] = f0.y; hrc[2] = f1.x; hrc[3] = f1.y;
  }
#pragma unroll
  for (int j = 0; j < 4; j++) {
    int c = cg * 4 + j;
    av[j] = att[c]; w0[j] = We[c]; w1[j] = We[64 + c];
  }
  int b = ptr[d], en = ptr[d + 1];
  int en_ext = en + (SELF ? 1 : 0);
  for (int base = b + wv * 4; base < en_ext; base += 4 * nw) {
    int p = base + eg;
    int s = 0; float e0 = 0.f, e1 = 0.f;
    bool valid = p < en_ext;
    if (p < en) {
      Edge e = ed[p]; s = e.s;
      float2 f = __half22float2(e.ea); e0 = f.x; e1 = f.y;
    } else if (SELF && p == en) {
      s = d; e0 = mean_ea[2 * d]; e1 = mean_ea[2 * d + 1];
    }
    float hlv[4];
    {
      float2 r = *(const float2*)&hl[(size_t)s * 64 + cg * 4];
      const __half2* hp = (const __half2*)&r;
      float2 f0 = __half22float2(hp[0]), f1 = __half22float2(hp[1]);
      hlv[0] = f0.x; hlv[1] = f0.y; hlv[2] = f1.x; hlv[3] = f1.y;
    }
    float l = 0.f;
#pragma unroll
    for (int j = 0; j < 4; j++) {
      float g = hlv[j] + hrc[j] + e0 * w0[j] + e1 * w1[j];
      g = g > 0.f ? g : 0.2f * g;
      l = fmaf(g, av[j], l);
    }
#pragma unroll
    for (int o = 1; o <= 8; o <<= 1) l += __shfl_xor(l, o);
    float ex = valid ? __expf(l) : 0.f;
#pragma unroll
    for (int j = 0; j < 4; j++) acc[j] = fmaf(ex, hlv[j], acc[j]);
    den += ex;
  }
#pragma unroll
  for (int o = 16; o <= 32; o <<= 1) {
#pragma unroll
    for (int j = 0; j < 4; j++) acc[j] += __shfl_xor(acc[j], o);
    den += __shfl_xor(den, o);
  }
}

// layer-1 merged: blocks [0,VB) = veh (wave/dst), [VB,VB+NR) = rsu (block/dst)
__global__ __launch_bounds__(256) void k_gat_l1(
    const int* ptr_vv, const Edge* e_vv, const float* mean_ea,
    const __half* hl_vv, const __half* hr_vv, const float* We_vv, const float* att_vv,
    const int* ptr_iv, const Edge* e_iv,
    const __half* hl_iv, const __half* hr_iv, const float* We_iv, const float* att_iv,
    const int* ptr_vi, const Edge* e_vi,
    const __half* hl_vi, const __half* hr_vi, const float* We_vi, const float* att_vi,
    const float* b_vv, const float* b_iv, const float* b_vi,
    __half* __restrict__ v1, __half* __restrict__ r1) {
  __shared__ float sm[4][16][10];
  int lane = threadIdx.x & 63, wv = threadIdx.x >> 6;
  int eg = lane >> 4, cg = lane & 15;
  if (blockIdx.x < VB) {
    int w = blockIdx.x * 4 + wv;
    if (w >= NV) return;
    float acc[8] = {0, 0, 0, 0, 0, 0, 0, 0};
    float d0 = 0.f, d1 = 0.f, oc[8];
    gatT2<true>(w, eg, cg, 0, 1, mean_ea, ptr_vv, e_vv, hl_vv, hr_vv, We_vv, att_vv, acc, d0, d1);
#pragma unroll
    for (int j = 0; j < 8; j++) oc[j] = acc[j] / (((j & 1) ? d1 : d0) + 1e-16f);
#pragma unroll
    for (int j = 0; j < 8; j++) acc[j] = 0.f;
    d0 = d1 = 0.f;
    gatT2<false>(w, eg, cg, 0, 1, nullptr, ptr_iv, e_iv, hl_iv, hr_iv, We_iv, att_iv, acc, d0, d1);
#pragma unroll
    for (int j = 0; j < 8; j++) oc[j] += acc[j] / (((j & 1) ? d1 : d0) + 1e-16f);
    if (eg == 0) {
#pragma unroll
      for (int j = 0; j < 8; j++) {
        int p = cg * 8 + j;
        int idx = (p & 1) * 64 + (p >> 1);
        float x = oc[j] + b_vv[idx] + b_iv[idx];
        x = x > 0.f ? x : __expf(x) - 1.f;
        v1[(size_t)w * 128 + idx] = __float2half(x);
      }
    }
  } else {
    int dd = blockIdx.x - VB;
    float acc[8] = {0, 0, 0, 0, 0, 0, 0, 0};
    float d0 = 0.f, d1 = 0.f;
    gatT2<false>(dd, eg, cg, wv, 4, nullptr, ptr_vi, e_vi, hl_vi, hr_vi, We_vi, att_vi, acc, d0, d1);
    if (eg == 0) {
#pragma unroll
      for (int j = 0; j < 8; j++) sm[wv][cg][j] = acc[j];
      sm[wv][cg][8] = d0; sm[wv][cg][9] = d1;
    }
    __syncthreads();
    if (wv == 0 && eg == 0) {
#pragma unroll
      for (int j = 0; j < 8; j++)
        acc[j] = sm[0][cg][j] + sm[1][cg][j] + sm[2][cg][j] + sm[3][cg][j];
      d0 = sm[0][cg][8] + sm[1][cg][8] + sm[2][cg][8] + sm[3][cg][8];
      d1 = sm[0][cg][9] + sm[1][cg][9] + sm[2][cg][9] + sm[3][cg][9];
#pragma unroll
      for (int j = 0; j < 8; j++) {
        int p = cg * 8 + j;
        int idx = (p & 1) * 64 + (p >> 1);
        float x = acc[j] / (((j & 1) ? d1 : d0) + 1e-16f) + b_vi[idx];
        x = x > 0.f ? x : __expf(x) - 1.f;
        r1[(size_t)dd * 128 + idx] = __float2half(x);
      }
    }
  }
}

// layer-2 merged: veh rows -> out[0..NV), rsu rows -> out[NV..NV+NR)
__global__ __launch_bounds__(256) void k_gat_l2(
    const int* ptr_vv, const Edge* e_vv, const float* mean_ea,
    const __half* hl_vv, const __half* hr_vv, const float* We_vv, const float* att_vv,
    const int* ptr_iv, const Edge* e_iv,
    const __half* hl_iv, const __half* hr_iv, const float* We_iv, const float* att_iv,
    const int* ptr_vi, const Edge* e_vi,
    const __half* hl_vi, const __half* hr_vi, const float* We_vi, const float* att_vi,
    const float* b_vv, const float* b_iv, const float* b_vi,
    const float* ln_vg, const float* ln_vb, const float* ln_rg, const float* ln_rb,
    float* __restrict__ out) {
  __shared__ float sm[4][16][5];
  int lane = threadIdx.x & 63, wv = threadIdx.x >> 6;
  int eg = lane >> 4, cg = lane & 15;
  if (blockIdx.x < VB) {
    int w = blockIdx.x * 4 + wv;
    if (w >= NV) return;
    float acc[4] = {0, 0, 0, 0};
    float dn = 0.f, oc[4];
    gatT1<true>(w, eg, cg, 0, 1, mean_ea, ptr_vv, e_vv, hl_vv, hr_vv, We_vv, att_vv, acc, dn);
#pragma unroll
    for (int j = 0; j < 4; j++) oc[j] = acc[j] / (dn + 1e-16f);
#pragma unroll
    for (int j = 0; j < 4; j++) acc[j] = 0.f;
    dn = 0.f;
    gatT1<false>(w, eg, cg, 0, 1, nullptr, ptr_iv, e_iv, hl_iv, hr_iv, We_iv, att_iv, acc, dn);
#pragma unroll
    for (int j = 0; j < 4; j++) oc[j] += acc[j] / (dn + 1e-16f);
    float x[4];
#pragma unroll
    for (int j = 0; j < 4; j++) {
      int c = cg * 4 + j;
      x[j] = oc[j] + b_vv[c] + b_iv[c];
    }
    float s = x[0] + x[1] + x[2] + x[3];
#pragma unroll
    for (int o = 1; o <= 8; o <<= 1) s += __shfl_xor(s, o);
    float mu = s * (1.f / 64.f);
    float v = 0.f;
#pragma unroll
    for (int j = 0; j < 4; j++) { float dx = x[j] - mu; v = fmaf(dx, dx, v); }
#pragma unroll
    for (int o = 1; o <= 8; o <<= 1) v += __shfl_xor(v, o);
    float rstd = rsqrtf(v * (1.f / 64.f) + 1e-5f);
    if (eg == 0) {
#pragma unroll
      for (int j = 0; j < 4; j++) {
        int c = cg * 4 + j;
        out[(size_t)w * 64 + c] = (x[j] - mu) * rstd * ln_vg[c] + ln_vb[c];
      }
    }
  } else {
    int dd = blockIdx.x - VB;
    float acc[4] = {0, 0, 0, 0};
    float dn = 0.f;
    gatT1<false>(dd, eg, cg, wv, 4, nullptr, ptr_vi, e_vi, hl_vi, hr_vi, We_vi, att_vi, acc, dn);
    if (eg == 0) {
#pragma unroll
      for (int j = 0; j < 4; j++) sm[wv][cg][j] = acc[j];
      sm[wv][cg][4] = dn;
    }
    __syncthreads();
    if (wv == 0) {
#pragma unroll
      for (int j = 0; j < 4; j++)
        acc[j] = sm[0][cg][j] + sm[1][cg][j] + sm[2][cg][j] + sm[3][cg][j];
      dn = sm[0][cg][4] + sm[1][cg][4] + sm[2][cg][4] + sm[3][cg][4];
      float x[4];
#pragma unroll
      for (int j = 0; j < 4; j++) {
        int c = cg * 4 + j;
        x[j] = acc[j] / (dn + 1e-16f) + b_vi[c];
      }
      float s = x[0] + x[1] + x[2] + x[3];
#pragma unroll
      for (int o = 1; o <= 8; o <<= 1) s += __shfl_xor(s, o);
      float mu = s * (1.f / 64.f);
      float v = 0.f;
#pragma unroll
      for (int j = 0; j < 4; j++) { float dx = x[j] - mu; v = fmaf(dx, dx, v); }
#pragma unroll
      for (int o = 1; o <= 8; o <<= 1) v += __shfl_xor(v, o);
      float rstd = rsqrtf(v * (1.f / 64.f) + 1e-5f);
      if (eg == 0) {
#pragma unroll
        for (int j = 0; j < 4; j++) {
          int c = cg * 4 + j;
          out[(size_t)(NV + dd) * 64 + c] = (x[j] - mu) * rstd * ln_rg[c] + ln_rb[c];
        }
      }
    }
  }
}

// ---------------- launch ----------------
extern "C" void kernel_launch(void* const* d_in, const int* in_sizes, int n_in,
                              void* d_out, int out_size, void* d_ws, size_t ws_size,
                              hipStream_t stream) {
  const float* x_veh  = (const float*)d_in[0];
  const float* x_rsu  = (const float*)d_in[1];
  const float* ea_vv  = (const float*)d_in[2];
  const float* ea_vi  = (const float*)d_in[3];
  const float* ea_iv  = (const float*)d_in[4];
  const int*   src_vv = (const int*)d_in[5];
  const int*   dst_vv = (const int*)d_in[6];
  const int*   src_vi = (const int*)d_in[7];
  const int*   dst_vi = (const int*)d_in[8];
  const int*   src_iv = (const int*)d_in[9];
  const int*   dst_iv = (const int*)d_in[10];
  const float* Wl_vv1 = (const float*)d_in[11];
  const float* Wr_vv1 = (const float*)d_in[12];
  const float* We_vv1 = (const float*)d_in[13];
  const float* att_vv1= (const float*)d_in[14];
  const float* b_vv1  = (const float*)d_in[15];
  const float* Wl_vi1 = (const float*)d_in[16];
  const float* Wr_vi1 = (const float*)d_in[17];
  const float* We_vi1 = (const float*)d_in[18];
  const float* att_vi1= (const float*)d_in[19];
  const float* b_vi1  = (const float*)d_in[20];
  const float* Wl_iv1 = (const float*)d_in[21];
  const float* Wr_iv1 = (const float*)d_in[22];
  const float* We_iv1 = (const float*)d_in[23];
  const float* att_iv1= (const float*)d_in[24];
  const float* b_iv1  = (const float*)d_in[25];
  const float* Wl_vv2 = (const float*)d_in[26];
  const float* Wr_vv2 = (const float*)d_in[27];
  const float* We_vv2 = (const float*)d_in[28];
  const float* att_vv2= (const float*)d_in[29];
  const float* b_vv2  = (const float*)d_in[30];
  const float* Wl_vi2 = (const float*)d_in[31];
  const float* Wr_vi2 = (const float*)d_in[32];
  const float* We_vi2 = (const float*)d_in[33];
  const float* att_vi2= (const float*)d_in[34];
  const float* b_vi2  = (const float*)d_in[35];
  const float* Wl_iv2 = (const float*)d_in[36];
  const float* Wr_iv2 = (const float*)d_in[37];
  const float* We_iv2 = (const float*)d_in[38];
  const float* att_iv2= (const float*)d_in[39];
  const float* b_iv2  = (const float*)d_in[40];
  const float* ln_vg  = (const float*)d_in[41];
  const float* ln_vb  = (const float*)d_in[42];
  const float* ln_rg  = (const float*)d_in[43];
  const float* ln_rb  = (const float*)d_in[44];

  float* ws  = (float*)d_ws;
  float* out = (float*)d_out;

  int* cnt_vv = (int*)(ws + OFF_CNT_VV); int* cur_vv = (int*)(ws + OFF_CUR_VV);
  int* cnt_iv = (int*)(ws + OFF_CNT_IV); int* cur_iv = (int*)(ws + OFF_CUR_IV);
  int* cnt_vi = (int*)(ws + OFF_CNT_VI); int* cur_vi = (int*)(ws + OFF_CUR_VI);
  int* ptr_vv = (int*)(ws + OFF_PTR_VV);
  int* ptr_iv = (int*)(ws + OFF_PTR_IV);
  int* ptr_vi = (int*)(ws + OFF_PTR_VI);
  float* mean = ws + OFF_MEAN;
  Edge* e_vv = (Edge*)(ws + OFF_E_VV);
  Edge* e_iv = (Edge*)(ws + OFF_E_IV);
  Edge* e_vi = (Edge*)(ws + OFF_E_VI);

  __half* hl_vv1 = (__half*)(ws + OFF_HL_VV1);
  __half* hr_vv1 = (__half*)(ws + OFF_HR_VV1);
  __half* hr_iv1 = (__half*)(ws + OFF_HR_IV1);
  __half* hl_vi1 = (__half*)(ws + OFF_HL_VI1);
  __half* hl_iv1 = (__half*)(ws + OFF_HL_IV1);
  __half* hr_vi1 = (__half*)(ws + OFF_HR_VI1);
  __half* v1 = (__half*)(ws + OFF_V1);
  __half* r1 = (__half*)(ws + OFF_R1);
  __half* hl_vv2 = (__half*)(ws + OFF_HL_VV2);
  __half* hr_vv2 = (__half*)(ws + OFF_HR_VV2);
  __half* hr_iv2 = (__half*)(ws + OFF_HR_IV2);
  __half* hl_vi2 = (__half*)(ws + OFF_HL_VI2);
  __half* hl_iv2 = (__half*)(ws + OFF_HL_IV2);
  __half* hr_vi2 = (__half*)(ws + OFF_HR_VI2);

  hipMemsetAsync(ws, 0, ZERO_END * sizeof(float), stream);

  k_count3<<<(ETOT + 255) / 256, 256, 0, stream>>>(dst_vv, dst_iv, dst_vi,
      cnt_vv, cnt_iv, cnt_vi);
  k_scan3<<<3, 1024, 0, stream>>>(cnt_vv, ptr_vv, NV, cnt_iv, ptr_iv, NV, cnt_vi, ptr_vi, NR);
  k_fill3<<<(ETOT + 255) / 256, 256, 0, stream>>>(
      src_vv, dst_vv, ea_vv, src_iv, dst_iv, ea_iv, src_vi, dst_vi, ea_vi,
      ptr_vv, cur_vv, e_vv, ptr_iv, cur_iv, e_iv, ptr_vi, cur_vi, e_vi);
  k_mean_seg<<<(NV + 255) / 256, 256, 0, stream>>>(ptr_vv, e_vv, mean, NV);

  // layer-1 dense transforms (head-interleaved fp16 outputs)
  k_gemm1<16, 4><<<(NV + 31) / 32, 256, 0, stream>>>(x_veh,
      Wl_vv1, Wr_vv1, Wr_iv1, Wl_vi1, hl_vv1, hr_vv1, hr_iv1, hl_vi1, NV);
  k_gemm1<8, 2><<<(NR + 31) / 32, 256, 0, stream>>>(x_rsu,
      Wl_iv1, Wr_vi1, nullptr, nullptr, hl_iv1, hr_vi1, nullptr, nullptr, NR);

  // layer-1 fused aggregation (transposed lanes; rsu blocks appended)
  k_gat_l1<<<VB + NR, 256, 0, stream>>>(
      ptr_vv, e_vv, mean,
      hl_vv1, hr_vv1, We_vv1, att_vv1,
      ptr_iv, e_iv, hl_iv1, hr_iv1, We_iv1, att_iv1,
      ptr_vi, e_vi, hl_vi1, hr_vi1, We_vi1, att_vi1,
      b_vv1, b_iv1, b_vi1, v1, r1);

  // layer-2 dense transforms
  k_gemm2<4><<<(NV + 31) / 32, 256, 0, stream>>>(v1,
      Wl_vv2, Wr_vv2, Wr_iv2, Wl_vi2, hl_vv2, hr_vv2, hr_iv2, hl_vi2, NV);
  k_gemm2<2><<<(NR + 31) / 32, 128, 0, stream>>>(r1,
      Wl_iv2, Wr_vi2, nullptr, nullptr, hl_iv2, hr_vi2, nullptr, nullptr, NR);

  // layer-2 fused aggregation + LayerNorm -> out
  k_gat_l2<<<VB + NR, 256, 0, stream>>>(
      ptr_vv, e_vv, mean,
      hl_vv2, hr_vv2, We_vv2, att_vv2,
      ptr_iv, e_iv, hl_iv2, hr_iv2, We_iv2, att_iv2,
      ptr_vi, e_vi, hl_vi2, hr_vi2, We_vi2, att_vi2,
      b_vv2, b_iv2, b_vi2, ln_vg, ln_vb, ln_rg, ln_rb, out);
  (void)in_sizes; (void)n_in; (void)out_size; (void)ws_size;
}